// Round 1
// baseline (26168.109 us; speedup 1.0000x reference)
//
#include <hip/hip_runtime.h>
#include <hip/hip_bf16.h>
#include <stdint.h>

// LSTM_48601849922171 — 2-layer LSTM (B=8, T=2048, D_IN=256, H=512), fp32 I/O,
// bf16 MFMA compute.
//
// Round 8: XCD-clustered recurrence + L2-local sync.
// R7 diagnosis: 5.57us/step with all pipes idle (MfmaUtil 0.7%, HBM 0.7%,
// heater-neutral) => the cost is agent-scope (MALL-distance) store->load
// visibility plus a 1024-line-transaction poll sweep per wave. Fix:
//   - All 128 rec waves on ONE XCD, found at runtime via HW_REG_XCC_ID +
//     ticket claim. 56KB LDS forces exactly 2 blocks/CU, so the 512-block
//     grid fills every CU => exactly 64 blocks/XCD => XCD0's 64 blocks claim
//     all 64 tickets. Per claimed block: wave0 = L0 rec, wave1 = L1 rec
//     (L0->L1 handoff also intra-XCD), waves 2-3 = heater.
//   - h exchange via XCD-local L2: plain stores (write-through L1->L2) +
//     sc0 poll loads (bypass L1, hit L2). ~200cy visibility vs multi-us MALL.
//   - Coalesced poll: lane l reads 16B of each 1KB chunk => 8x dwordx4
//     (64 line-requests/wave/sweep vs 1024 scattered 8B requests).
//   - Fail-safe: same-address agent shadow store + agent sweep every 8th
//     poll iteration, so a wrong clustering assumption degrades to ~R7 perf
//     instead of hanging (poll guard additionally caps at 1<<14 iters).
//
// Workspace (~111 MB):
//   0:        payl0 [2048][64][16] u64 = 16 MB  (memset 0xFF)
//   16M:      payl1 16 MB                        (memset 0xFF)
//   32M:      Wb0 1MB | 33M: Ub0 2MB | 35M: Wb1 2MB | 37M: Ub1 2MB
//   39M:      wx0 [2048][8][2048] bf16 = 64 MB
//   115343360: done u32, claim u32 (memset 0)

typedef __hip_bfloat16 bf16;
typedef float  floatx4 __attribute__((ext_vector_type(4)));
typedef short  short8  __attribute__((ext_vector_type(8)));
typedef short  short4v __attribute__((ext_vector_type(4)));
typedef unsigned int u32x4 __attribute__((ext_vector_type(4)));
typedef unsigned long long u64;

#define T_STEPS  2048
#define SENT32   0xFFFFFFFFu
#define HH_OFF   8388608   // 8*2048*512
#define CC_OFF   8396800   // HH_OFF + 2*8*512
#define STR0     1056      // LDS row stride bytes, layer 0 ([8][512+pad])
#define STR1     2080      // LDS row stride bytes, layer 1 ([8][1024+pad])
#define N_REC    128       // rec waves total (64 blocks x 2)
#define N_BLK    512
#define GUARD_MAX (1 << 14)

static __device__ __forceinline__ float bs2f(short s) {
  union { unsigned int u; float f; } c;
  c.u = ((unsigned int)(unsigned short)s) << 16;
  return c.f;
}
static __device__ __forceinline__ short f2bs(float x) {
  union { bf16 h; short s; } u;
  u.h = __float2bfloat16(x);
  return u.s;
}
static __device__ __forceinline__ float sigm(float x) {
  x = fminf(fmaxf(x, -30.f), 30.f);
  return 1.f / (1.f + __expf(-x));
}
static __device__ __forceinline__ float tanhf_(float x) {
  x = fminf(fmaxf(x, -15.f), 15.f);
  float e = __expf(2.f * x);
  return (e - 1.f) / (e + 1.f);
}
static __device__ __forceinline__ floatx4 mfma_bf16(short8 a, short8 b, floatx4 c) {
  return __builtin_amdgcn_mfma_f32_16x16x32_bf16(a, b, c, 0, 0, 0);
}
static __device__ __forceinline__ u64 cload(const u64* p) {
  return __hip_atomic_load(p, __ATOMIC_RELAXED, __HIP_MEMORY_SCOPE_AGENT);
}
static __device__ __forceinline__ void cstore(u64* p, u64 v) {
  __hip_atomic_store(p, v, __ATOMIC_RELAXED, __HIP_MEMORY_SCOPE_AGENT);
}
// Plain store: write-through L1 into the XCD-local L2 (fast intra-XCD path).
static __device__ __forceinline__ void stg64(u64* p, u64 v) {
  asm volatile("global_store_dwordx2 %0, %1, off" :: "v"(p), "v"(v) : "memory");
}

// Coalesced sweep of one 8KB payload: chunk j (1KB), lane reads bytes
// [j*1024 + lane*16, +16). sc0 = bypass L1, serve from XCD-local L2.
static __device__ __forceinline__ void load8x16_sc0(const char* p, u32x4* w) {
  const char* p2 = p + 4096;
  asm volatile(
      "global_load_dwordx4 %[a0], %[p], off sc0\n\t"
      "global_load_dwordx4 %[a1], %[p], off offset:1024 sc0\n\t"
      "global_load_dwordx4 %[a2], %[p], off offset:2048 sc0\n\t"
      "global_load_dwordx4 %[a3], %[p], off offset:3072 sc0\n\t"
      "global_load_dwordx4 %[a4], %[q], off sc0\n\t"
      "global_load_dwordx4 %[a5], %[q], off offset:1024 sc0\n\t"
      "global_load_dwordx4 %[a6], %[q], off offset:2048 sc0\n\t"
      "global_load_dwordx4 %[a7], %[q], off offset:3072 sc0\n\t"
      "s_waitcnt vmcnt(0)"
      : [a0]"=v"(w[0]), [a1]"=v"(w[1]), [a2]"=v"(w[2]), [a3]"=v"(w[3]),
        [a4]"=v"(w[4]), [a5]"=v"(w[5]), [a6]"=v"(w[6]), [a7]"=v"(w[7])
      : [p]"v"(p), [q]"v"(p2)
      : "memory");
}
// Agent-scope fallback sweep (MALL-coherent) — same addressing.
static __device__ __forceinline__ void load8x16_agent(const char* p, u32x4* w) {
  #pragma unroll
  for (int j = 0; j < 8; ++j) {
    u64 lo = cload(reinterpret_cast<const u64*>(p + j * 1024));
    u64 hi = cload(reinterpret_cast<const u64*>(p + j * 1024 + 8));
    u32x4 v;
    v.x = (unsigned)lo; v.y = (unsigned)(lo >> 32);
    v.z = (unsigned)hi; v.w = (unsigned)(hi >> 32);
    w[j] = v;
  }
}
// Sentinel check per 8B half (h>=0 => packed bf16 words never all-ones).
static __device__ __forceinline__ int valid8(const u32x4* w) {
  int ok = 1;
  #pragma unroll
  for (int j = 0; j < 8; ++j) {
    ok &= ((w[j].x & w[j].y) != SENT32);
    ok &= ((w[j].z & w[j].w) != SENT32);
  }
  return ok;
}

// fp32 -> bf16 elementwise (n multiple of 4)
__global__ __launch_bounds__(256)
void cvt_f32_bf16(const float* __restrict__ src, bf16* __restrict__ dst, int n) {
  int i = (blockIdx.x * 256 + threadIdx.x) * 4;
  if (i < n) {
    floatx4 v = *reinterpret_cast<const floatx4*>(src + i);
    short4v o;
    #pragma unroll
    for (int r = 0; r < 4; ++r) o[r] = f2bs(v[r]);
    *reinterpret_cast<short4v*>(dst + i) = o;
  }
}

// ---------------------------------------------------------------------------
// Layer-0 input projection: out[m][n] = sum_k A[m][k]*W[n][k] + bias[n],
// m = t*8+b. Block 256 thr; wave tile M=16 x N=64; grid (1024, 8).
// ---------------------------------------------------------------------------
__global__ __launch_bounds__(256)
void gemm_proj(const float* __restrict__ Af, const bf16* __restrict__ W,
               const float* __restrict__ bias, bf16* __restrict__ out,
               int K, int strideB, int strideT)
{
  const int lane  = threadIdx.x & 63;
  const int wave  = threadIdx.x >> 6;
  const int q     = lane >> 4;
  const int c     = lane & 15;
  const int mtile = blockIdx.x;
  const int nbase = blockIdx.y * 256 + wave * 64;
  const int m     = mtile * 16 + c;

  const long abase = (long)(m & 7) * strideB + (long)(m >> 3) * strideT + q * 8;
  const bf16* W0 = W + (long)(nbase +  0 + c) * K + q * 8;
  const bf16* W1 = W + (long)(nbase + 16 + c) * K + q * 8;
  const bf16* W2 = W + (long)(nbase + 32 + c) * K + q * 8;
  const bf16* W3 = W + (long)(nbase + 48 + c) * K + q * 8;

  floatx4 acc0 = {0.f, 0.f, 0.f, 0.f};
  floatx4 acc1 = acc0, acc2 = acc0, acc3 = acc0;
  const int nk = K >> 5;
  for (int kt = 0; kt < nk; ++kt) {
    short8 a;
    floatx4 lo = *reinterpret_cast<const floatx4*>(Af + abase + kt * 32);
    floatx4 hi = *reinterpret_cast<const floatx4*>(Af + abase + kt * 32 + 4);
    #pragma unroll
    for (int r = 0; r < 4; ++r) { a[r] = f2bs(lo[r]); a[4 + r] = f2bs(hi[r]); }
    short8 b0 = *reinterpret_cast<const short8*>(W0 + kt * 32);
    short8 b1 = *reinterpret_cast<const short8*>(W1 + kt * 32);
    short8 b2 = *reinterpret_cast<const short8*>(W2 + kt * 32);
    short8 b3 = *reinterpret_cast<const short8*>(W3 + kt * 32);
    acc0 = mfma_bf16(a, b0, acc0);
    acc1 = mfma_bf16(a, b1, acc1);
    acc2 = mfma_bf16(a, b2, acc2);
    acc3 = mfma_bf16(a, b3, acc3);
  }

  floatx4 accs[4] = {acc0, acc1, acc2, acc3};
  #pragma unroll
  for (int nt = 0; nt < 4; ++nt) {
    const int n = nbase + nt * 16 + c;
    const float bv = bias[n];
    #pragma unroll
    for (int r = 0; r < 4; ++r) {
      const int mrow = mtile * 16 + q * 4 + r;
      out[(long)mrow * 2048 + n] = __float2bfloat16(accs[nt][r] + bv);
    }
  }
}

// ---------------------------------------------------------------------------
// Fused 2-layer persistent recurrence, XCD-clustered. 512 blocks x 256 thr.
// 56KB LDS => exactly 2 blocks/CU => grid == residency capacity => exactly
// 64 blocks land on each XCD. Blocks on XCD0 claim tickets 0..63; ticket t:
// wave0 = layer0 blk t, wave1 = layer1 blk t, waves 2-3 heater. All other
// blocks: pure heater (keeps GFXCLK up; neutral but known-safe).
// ---------------------------------------------------------------------------
__global__ __launch_bounds__(256, 2)
void lstm_fused(const bf16* __restrict__ wx, const bf16* __restrict__ Ub0,
                const bf16* __restrict__ Wb1, const bf16* __restrict__ Ub1,
                const float* __restrict__ ub0, const float* __restrict__ w1b,
                const float* __restrict__ u1b, float* __restrict__ out,
                u64* __restrict__ payl0, u64* __restrict__ payl1,
                unsigned int* __restrict__ done, unsigned int* __restrict__ claim)
{
  __shared__ char lds[57344];     // inflated to force 2 blocks/CU
  __shared__ int s_role;
  if (threadIdx.x == 0) {
    int xcd = 0;
    asm volatile("s_getreg_b32 %0, hwreg(HW_REG_XCC_ID)" : "=s"(xcd));
    int role = -1;
    if ((xcd & 7) == 0) {
      unsigned int tk = __hip_atomic_fetch_add(claim, 1u, __ATOMIC_RELAXED,
                                               __HIP_MEMORY_SCOPE_AGENT);
      if (tk < 64u) role = (int)tk;
    }
    s_role = role;
  }
  __syncthreads();
  const int role = s_role;
  const int wv   = threadIdx.x >> 6;

  if (role < 0 || wv >= 2) {
    // ---------------- heater ----------------
    float a0 = (float)threadIdx.x, a1 = a0 + 1.f, a2 = a0 + 2.f, a3 = a0 + 3.f;
    float a4 = a0 + 4.f, a5 = a0 + 5.f, a6 = a0 + 6.f, a7 = a0 + 7.f;
    const float xm = 1.0000001f, ya = 1e-7f;
    int g = 0;
    for (;;) {
      #pragma unroll
      for (int it = 0; it < 64; ++it) {
        asm volatile("v_fmac_f32 %0, %1, %2" : "+v"(a0) : "v"(xm), "v"(ya));
        asm volatile("v_fmac_f32 %0, %1, %2" : "+v"(a1) : "v"(xm), "v"(ya));
        asm volatile("v_fmac_f32 %0, %1, %2" : "+v"(a2) : "v"(xm), "v"(ya));
        asm volatile("v_fmac_f32 %0, %1, %2" : "+v"(a3) : "v"(xm), "v"(ya));
        asm volatile("v_fmac_f32 %0, %1, %2" : "+v"(a4) : "v"(xm), "v"(ya));
        asm volatile("v_fmac_f32 %0, %1, %2" : "+v"(a5) : "v"(xm), "v"(ya));
        asm volatile("v_fmac_f32 %0, %1, %2" : "+v"(a6) : "v"(xm), "v"(ya));
        asm volatile("v_fmac_f32 %0, %1, %2" : "+v"(a7) : "v"(xm), "v"(ya));
      }
      if (__hip_atomic_load(done, __ATOMIC_RELAXED,
                            __HIP_MEMORY_SCOPE_AGENT) >= (unsigned)N_REC) break;
      if (++g > (1 << 22)) break;
    }
    return;
  }

  // ---------------- recurrence (waves 0/1 of the 64 claimed blocks) --------
  asm volatile("s_setprio 3" ::: "memory");
  const int lane  = threadIdx.x & 63;
  const int q     = lane >> 4;
  const int b     = lane & 15;
  const int blk   = role;
  const int jbase = blk * 8;
  const int jj    = jbase + (q & 1) * 4;

  const int row0 = (b < 8) ? (jbase + b) : (512 + jbase + b - 8);           // i | f
  const int row1 = (b < 8) ? (1024 + jbase + b) : (1536 + jbase + b - 8);   // g | o

  float* hh = out + ((wv == 0) ? HH_OFF : HH_OFF + 4096);
  float* cc = out + ((wv == 0) ? CC_OFF : CC_OFF + 4096);

  if (wv == 0) {
    // ---- Layer 0: K=512 (U0 * h1(t-1)) + precomputed wx ----
    char* lds0 = lds;
    short8 a0[16], a1[16];
    {
      const bf16* U0p = Ub0 + (long)row0 * 512 + q * 8;
      const bf16* U1p = Ub0 + (long)row1 * 512 + q * 8;
      #pragma unroll
      for (int kt = 0; kt < 16; ++kt) {
        a0[kt] = *reinterpret_cast<const short8*>(U0p + kt * 32);
        a1[kt] = *reinterpret_cast<const short8*>(U1p + kt * 32);
      }
    }
    float ubi[4], ubf[4], ubg[4], ubo[4];
    #pragma unroll
    for (int r = 0; r < 4; ++r) {
      ubi[r] = ub0[        jj + r];
      ubf[r] = ub0[ 512 + jj + r];
      ubg[r] = ub0[1024 + jj + r];
      ubo[r] = ub0[1536 + jj + r];
    }
    float cst[4] = {0.f, 0.f, 0.f, 0.f};

    for (int t = 0; t < T_STEPS; ++t) {
      const bf16* wxp = wx + (long)t * 16384 + (b & 7) * 2048 + jj;
      short4v vi = *reinterpret_cast<const short4v*>(wxp);
      short4v vf = *reinterpret_cast<const short4v*>(wxp + 512);
      short4v vg = *reinterpret_cast<const short4v*>(wxp + 1024);
      short4v vo = *reinterpret_cast<const short4v*>(wxp + 1536);

      floatx4 acc0 = {0.f, 0.f, 0.f, 0.f};
      floatx4 acc1 = {0.f, 0.f, 0.f, 0.f};

      if (t > 0) {
        const char* pp =
            reinterpret_cast<const char*>(payl0 + (long)(t - 1) * 1024) + lane * 16;
        u32x4 w[8];
        int guard = 0;
        for (;;) {
          if ((guard & 7) == 7) load8x16_agent(pp, w);
          else                  load8x16_sc0(pp, w);
          if (__all(valid8(w))) break;
          if (++guard > GUARD_MAX) break;
        }
        #pragma unroll
        for (int j = 0; j < 8; ++j) {
          *reinterpret_cast<u32x4*>(
              lds0 + (lane & 7) * STR0 + ((lane >> 3) * 16) + j * 128) = w[j];
        }
        #pragma unroll
        for (int kt = 0; kt < 16; ++kt) {
          short8 hb = *reinterpret_cast<const short8*>(
              lds0 + (b & 7) * STR0 + kt * 64 + q * 16);
          acc0 = mfma_bf16(a0[kt], hb, acc0);
          acc1 = mfma_bf16(a1[kt], hb, acc1);
        }
      }

      float wxi[4], wxf[4], wxg[4], wxo[4];
      #pragma unroll
      for (int r = 0; r < 4; ++r) {
        wxi[r] = bs2f(vi[r]); wxf[r] = bs2f(vf[r]);
        wxg[r] = bs2f(vg[r]); wxo[r] = bs2f(vo[r]);
      }
      float fsh[4], osh[4];
      #pragma unroll
      for (int r = 0; r < 4; ++r) {
        fsh[r] = __shfl_xor(acc0[r], 32, 64);
        osh[r] = __shfl_xor(acc1[r], 32, 64);
      }

      if (q < 2 && b < 8) {
        short4v hp4; floatx4 hf4, cf4;
        #pragma unroll
        for (int r = 0; r < 4; ++r) {
          const float pi = acc0[r] + wxi[r] + ubi[r];
          const float pf = fsh[r]  + wxf[r] + ubf[r];
          const float pg = acc1[r] + wxg[r] + ubg[r];
          const float po = osh[r]  + wxo[r] + ubo[r];
          const float it = sigm(pi), ft = sigm(pf);
          const float gt = tanhf_(pg), ot = sigm(po);
          const float cv = ft * cst[r] + it * gt;
          cst[r] = cv;
          const float hv = ot * fmaxf(cv, 0.f);
          hf4[r] = hv; cf4[r] = cv; hp4[r] = f2bs(hv);
        }
        union { short4v v; u64 u; } pk; pk.v = hp4;
        u64* dst = payl0 + (long)t * 1024 + blk * 16 + (b * 2 + (q & 1));
        stg64(dst, pk.u);     // fast path: XCD-local L2
        cstore(dst, pk.u);    // shadow: MALL (agent fallback readers)
        if (t == T_STEPS - 1) {
          *reinterpret_cast<floatx4*>(hh + b * 512 + jj) = hf4;
          *reinterpret_cast<floatx4*>(cc + b * 512 + jj) = cf4;
        }
      }
    }
  } else {
    // ---- Layer 1: K=1024 ([W1|U1] * [h1(t); h2(t-1)]) ----
    char* lds1 = lds + 32768;
    short8 a0[32], a1[32];
    {
      const bf16* W0p = Wb1 + (long)row0 * 512 + q * 8;
      const bf16* W1p = Wb1 + (long)row1 * 512 + q * 8;
      const bf16* U0p = Ub1 + (long)row0 * 512 + q * 8;
      const bf16* U1p = Ub1 + (long)row1 * 512 + q * 8;
      #pragma unroll
      for (int kt = 0; kt < 16; ++kt) {
        a0[kt]      = *reinterpret_cast<const short8*>(W0p + kt * 32);
        a1[kt]      = *reinterpret_cast<const short8*>(W1p + kt * 32);
        a0[16 + kt] = *reinterpret_cast<const short8*>(U0p + kt * 32);
        a1[16 + kt] = *reinterpret_cast<const short8*>(U1p + kt * 32);
      }
    }
    float ubi[4], ubf[4], ubg[4], ubo[4];
    #pragma unroll
    for (int r = 0; r < 4; ++r) {
      ubi[r] = w1b[        jj + r] + u1b[        jj + r];
      ubf[r] = w1b[ 512 + jj + r] + u1b[ 512 + jj + r];
      ubg[r] = w1b[1024 + jj + r] + u1b[1024 + jj + r];
      ubo[r] = w1b[1536 + jj + r] + u1b[1536 + jj + r];
    }
    float cst[4] = {0.f, 0.f, 0.f, 0.f};

    for (int t = 0; t < T_STEPS; ++t) {
      floatx4 acc0 = {0.f, 0.f, 0.f, 0.f};
      floatx4 acc1 = {0.f, 0.f, 0.f, 0.f};

      const char* p0 =
          reinterpret_cast<const char*>(payl0 + (long)t * 1024) + lane * 16;
      u32x4 w0[8], w1r[8];
      int guard = 0;
      if (t > 0) {
        const char* p1 =
            reinterpret_cast<const char*>(payl1 + (long)(t - 1) * 1024) + lane * 16;
        for (;;) {
          if ((guard & 7) == 7) { load8x16_agent(p1, w1r); load8x16_agent(p0, w0); }
          else                  { load8x16_sc0(p1, w1r);   load8x16_sc0(p0, w0); }
          int ok = valid8(w1r) & valid8(w0);
          if (__all(ok)) break;
          if (++guard > GUARD_MAX) break;
        }
      } else {
        for (;;) {
          if ((guard & 7) == 7) load8x16_agent(p0, w0);
          else                  load8x16_sc0(p0, w0);
          if (__all(valid8(w0))) break;
          if (++guard > GUARD_MAX) break;
        }
      }
      #pragma unroll
      for (int j = 0; j < 8; ++j) {
        *reinterpret_cast<u32x4*>(
            lds1 + (lane & 7) * STR1 + ((lane >> 3) * 16) + j * 128) = w0[j];
      }
      if (t > 0) {
        #pragma unroll
        for (int j = 0; j < 8; ++j) {
          *reinterpret_cast<u32x4*>(
              lds1 + (lane & 7) * STR1 + 1024 + ((lane >> 3) * 16) + j * 128) = w1r[j];
        }
      }
      #pragma unroll
      for (int kt = 0; kt < 16; ++kt) {
        short8 hb = *reinterpret_cast<const short8*>(
            lds1 + (b & 7) * STR1 + kt * 64 + q * 16);
        acc0 = mfma_bf16(a0[kt], hb, acc0);
        acc1 = mfma_bf16(a1[kt], hb, acc1);
      }
      if (t > 0) {
        #pragma unroll
        for (int kt = 16; kt < 32; ++kt) {
          short8 hb = *reinterpret_cast<const short8*>(
              lds1 + (b & 7) * STR1 + kt * 64 + q * 16);
          acc0 = mfma_bf16(a0[kt], hb, acc0);
          acc1 = mfma_bf16(a1[kt], hb, acc1);
        }
      }

      float fsh[4], osh[4];
      #pragma unroll
      for (int r = 0; r < 4; ++r) {
        fsh[r] = __shfl_xor(acc0[r], 32, 64);
        osh[r] = __shfl_xor(acc1[r], 32, 64);
      }

      if (q < 2 && b < 8) {
        short4v hp4; floatx4 hf4, cf4;
        #pragma unroll
        for (int r = 0; r < 4; ++r) {
          const float pi = acc0[r] + ubi[r];
          const float pf = fsh[r]  + ubf[r];
          const float pg = acc1[r] + ubg[r];
          const float po = osh[r]  + ubo[r];
          const float it = sigm(pi), ft = sigm(pf);
          const float gt = tanhf_(pg), ot = sigm(po);
          const float cv = ft * cst[r] + it * gt;
          cst[r] = cv;
          const float hv = ot * fmaxf(cv, 0.f);
          hf4[r] = hv; cf4[r] = cv; hp4[r] = f2bs(hv);
        }
        union { short4v v; u64 u; } pk; pk.v = hp4;
        u64* dst = payl1 + (long)t * 1024 + blk * 16 + (b * 2 + (q & 1));
        stg64(dst, pk.u);     // fast path: XCD-local L2
        cstore(dst, pk.u);    // shadow: MALL (agent fallback readers)
        *reinterpret_cast<floatx4*>(out + (long)b * 1048576 + (long)t * 512 + jj) = hf4;
        if (t == T_STEPS - 1) {
          *reinterpret_cast<floatx4*>(hh + b * 512 + jj) = hf4;
          *reinterpret_cast<floatx4*>(cc + b * 512 + jj) = cf4;
        }
      }
    }
  }

  // Signal heaters to exit (one per rec wave; 64 blocks x 2 waves = 128).
  if (lane == 0) {
    __hip_atomic_fetch_add(done, 1u, __ATOMIC_RELAXED, __HIP_MEMORY_SCOPE_AGENT);
  }
}

extern "C" void kernel_launch(void* const* d_in, const int* in_sizes, int n_in,
                              void* d_out, int out_size, void* d_ws, size_t ws_size,
                              hipStream_t stream) {
  (void)in_sizes; (void)n_in; (void)out_size; (void)ws_size;
  const float* x   = (const float*)d_in[0];
  const float* w0w = (const float*)d_in[1];
  const float* w0b = (const float*)d_in[2];
  const float* u0w = (const float*)d_in[3];
  const float* u0b = (const float*)d_in[4];
  const float* w1w = (const float*)d_in[5];
  const float* w1b = (const float*)d_in[6];
  const float* u1w = (const float*)d_in[7];
  const float* u1b = (const float*)d_in[8];
  float* out = (float*)d_out;

  char* ws = (char*)d_ws;
  u64*  payl0 = (u64*)ws;
  u64*  payl1 = (u64*)(ws + (size_t)16777216);
  bf16* Wb0 = (bf16*)(ws + (size_t)33554432);
  bf16* Ub0 = (bf16*)(ws + (size_t)34603008);
  bf16* Wb1 = (bf16*)(ws + (size_t)36700160);
  bf16* Ub1 = (bf16*)(ws + (size_t)38797312);
  bf16* wx  = (bf16*)(ws + (size_t)40894464);
  unsigned int* done = (unsigned int*)(ws + (size_t)115343360);

  // Sentinel-fill payload arrays; zero the done+claim counters.
  hipMemsetAsync(ws, 0xFF, (size_t)33554432, stream);
  hipMemsetAsync(done, 0, 64, stream);

  // Weight conversions fp32 -> bf16.
  cvt_f32_bf16<<<512,  256, 0, stream>>>(w0w, Wb0, 524288);
  cvt_f32_bf16<<<1024, 256, 0, stream>>>(u0w, Ub0, 1048576);
  cvt_f32_bf16<<<1024, 256, 0, stream>>>(w1w, Wb1, 1048576);
  cvt_f32_bf16<<<1024, 256, 0, stream>>>(u1w, Ub1, 1048576);

  // Layer-0 input projection.
  dim3 gg(1024, 8, 1);
  gemm_proj<<<gg, 256, 0, stream>>>(x, Wb0, w0b, wx, 256, 2048 * 256, 256);

  // Fused 2-layer recurrence (XCD-clustered) + heaters.
  lstm_fused<<<N_BLK, 256, 0, stream>>>(wx, Ub0, Wb1, Ub1, u0b, w1b, u1b,
                                        out, payl0, payl1, done, done + 1);
}

// Round 2
// 14012.149 us; speedup vs baseline: 1.8675x; 1.8675x over previous
//
#include <hip/hip_runtime.h>
#include <hip/hip_bf16.h>
#include <stdint.h>

// LSTM_48601849922171 — 2-layer LSTM (B=8, T=2048, D_IN=256, H=512), fp32 I/O,
// bf16 MFMA compute.
//
// Round 9: revert to R7 structure (known-good 11.4ms; R8's XCD-clustering
// regressed 2.3x because __launch_bounds__(256,2) capped VGPR 208->128 and
// spilled the 256-VGPR layer-1 weight arrays to scratch on the critical path).
// Isolated change vs R7: replace the sentinel poll flood (1024 distinct 8B
// agent loads per sweep per wave ~ 131k MALL transactions/round) with:
//   - flags0/flags1[t][64] u32: producer wave stores its 16x8B payload
//     (agent relaxed), then lane0 RELEASE-stores flag=1 (s_waitcnt vmcnt(0)
//     before the flag store orders the whole wave's payload stores).
//   - consumer polls 64 flags with ONE 4B relaxed load per lane (2 lines
//     total), acquire fence, then ONE coalesced bulk fetch of the 8KB
//     payload: 16 stride-16B u64 agent loads/lane (remap verified by R8's
//     passing run: payload u64 idx p=128j+2*lane -> LDS row=lane&7,
//     col=(lane>>3)*16 + j*128 (+8 for odd)).
//   - payload sentinel memset (32MB 0xFF) dropped; flags (1MB) zeroed.
//
// Workspace (~111 MB):
//   0:        payl0 [2048][64][16] u64 = 16 MB
//   16M:      payl1 16 MB
//   32M:      Wb0 1MB | 33M: Ub0 2MB | 35M: Wb1 2MB | 37M: Ub1 2MB
//   39M:      wx0 [2048][8][2048] bf16 = 64 MB   (ends 108003328)
//   108003328: flags0 [2048][64] u32 = 512 KB    (memset 0)
//   108527616: flags1 512 KB                     (memset 0)
//   115343360: done u32 (memset 0)

typedef __hip_bfloat16 bf16;
typedef float  floatx4 __attribute__((ext_vector_type(4)));
typedef short  short8  __attribute__((ext_vector_type(8)));
typedef short  short4v __attribute__((ext_vector_type(4)));
typedef unsigned long long u64;

#define T_STEPS  2048
#define HH_OFF   8388608   // 8*2048*512
#define CC_OFF   8396800   // HH_OFF + 2*8*512
#define STR0     1056      // LDS row stride bytes, layer 0 ([8][512+pad])
#define STR1     2080      // LDS row stride bytes, layer 1 ([8][1024+pad])
#define N_REC_BLK 128
#define N_BLK     512
#define GUARD_MAX (1 << 20)

static __device__ __forceinline__ float bs2f(short s) {
  union { unsigned int u; float f; } c;
  c.u = ((unsigned int)(unsigned short)s) << 16;
  return c.f;
}
static __device__ __forceinline__ short f2bs(float x) {
  union { bf16 h; short s; } u;
  u.h = __float2bfloat16(x);
  return u.s;
}
static __device__ __forceinline__ float sigm(float x) {
  x = fminf(fmaxf(x, -30.f), 30.f);
  return 1.f / (1.f + __expf(-x));
}
static __device__ __forceinline__ float tanhf_(float x) {
  x = fminf(fmaxf(x, -15.f), 15.f);
  float e = __expf(2.f * x);
  return (e - 1.f) / (e + 1.f);
}
static __device__ __forceinline__ floatx4 mfma_bf16(short8 a, short8 b, floatx4 c) {
  return __builtin_amdgcn_mfma_f32_16x16x32_bf16(a, b, c, 0, 0, 0);
}
static __device__ __forceinline__ u64 cload(const u64* p) {
  return __hip_atomic_load(p, __ATOMIC_RELAXED, __HIP_MEMORY_SCOPE_AGENT);
}
static __device__ __forceinline__ void cstore(u64* p, u64 v) {
  __hip_atomic_store(p, v, __ATOMIC_RELAXED, __HIP_MEMORY_SCOPE_AGENT);
}

// Bulk coalesced payload fetch -> LDS. pb points at payl[t]*1024 u64s.
// Lane reads bytes {j*1024 + lane*16, +8} for j=0..7 (fully coalesced),
// writes LDS row (lane&7), col (lane>>3)*16 + j*128 (+ colOff).
static __device__ __forceinline__ void fetch_payl(const u64* pb, int lane,
                                                  char* ldsbase, int stride,
                                                  int colOff) {
  u64 q0[8], q1[8];
  #pragma unroll
  for (int j = 0; j < 8; ++j) {
    q0[j] = cload(pb + j * 128 + lane * 2);
    q1[j] = cload(pb + j * 128 + lane * 2 + 1);
  }
  #pragma unroll
  for (int j = 0; j < 8; ++j) {
    char* d = ldsbase + (lane & 7) * stride + colOff + ((lane >> 3) * 16) + j * 128;
    *reinterpret_cast<u64*>(d)     = q0[j];
    *reinterpret_cast<u64*>(d + 8) = q1[j];
  }
}

// fp32 -> bf16 elementwise (n multiple of 4)
__global__ __launch_bounds__(256)
void cvt_f32_bf16(const float* __restrict__ src, bf16* __restrict__ dst, int n) {
  int i = (blockIdx.x * 256 + threadIdx.x) * 4;
  if (i < n) {
    floatx4 v = *reinterpret_cast<const floatx4*>(src + i);
    short4v o;
    #pragma unroll
    for (int r = 0; r < 4; ++r) o[r] = f2bs(v[r]);
    *reinterpret_cast<short4v*>(dst + i) = o;
  }
}

// ---------------------------------------------------------------------------
// Layer-0 input projection: out[m][n] = sum_k A[m][k]*W[n][k] + bias[n],
// m = t*8+b. Block 256 thr; wave tile M=16 x N=64; grid (1024, 8).
// ---------------------------------------------------------------------------
__global__ __launch_bounds__(256)
void gemm_proj(const float* __restrict__ Af, const bf16* __restrict__ W,
               const float* __restrict__ bias, bf16* __restrict__ out,
               int K, int strideB, int strideT)
{
  const int lane  = threadIdx.x & 63;
  const int wave  = threadIdx.x >> 6;
  const int q     = lane >> 4;
  const int c     = lane & 15;
  const int mtile = blockIdx.x;
  const int nbase = blockIdx.y * 256 + wave * 64;
  const int m     = mtile * 16 + c;

  const long abase = (long)(m & 7) * strideB + (long)(m >> 3) * strideT + q * 8;
  const bf16* W0 = W + (long)(nbase +  0 + c) * K + q * 8;
  const bf16* W1 = W + (long)(nbase + 16 + c) * K + q * 8;
  const bf16* W2 = W + (long)(nbase + 32 + c) * K + q * 8;
  const bf16* W3 = W + (long)(nbase + 48 + c) * K + q * 8;

  floatx4 acc0 = {0.f, 0.f, 0.f, 0.f};
  floatx4 acc1 = acc0, acc2 = acc0, acc3 = acc0;
  const int nk = K >> 5;
  for (int kt = 0; kt < nk; ++kt) {
    short8 a;
    floatx4 lo = *reinterpret_cast<const floatx4*>(Af + abase + kt * 32);
    floatx4 hi = *reinterpret_cast<const floatx4*>(Af + abase + kt * 32 + 4);
    #pragma unroll
    for (int r = 0; r < 4; ++r) { a[r] = f2bs(lo[r]); a[4 + r] = f2bs(hi[r]); }
    short8 b0 = *reinterpret_cast<const short8*>(W0 + kt * 32);
    short8 b1 = *reinterpret_cast<const short8*>(W1 + kt * 32);
    short8 b2 = *reinterpret_cast<const short8*>(W2 + kt * 32);
    short8 b3 = *reinterpret_cast<const short8*>(W3 + kt * 32);
    acc0 = mfma_bf16(a, b0, acc0);
    acc1 = mfma_bf16(a, b1, acc1);
    acc2 = mfma_bf16(a, b2, acc2);
    acc3 = mfma_bf16(a, b3, acc3);
  }

  floatx4 accs[4] = {acc0, acc1, acc2, acc3};
  #pragma unroll
  for (int nt = 0; nt < 4; ++nt) {
    const int n = nbase + nt * 16 + c;
    const float bv = bias[n];
    #pragma unroll
    for (int r = 0; r < 4; ++r) {
      const int mrow = mtile * 16 + q * 4 + r;
      out[(long)mrow * 2048 + n] = __float2bfloat16(accs[nt][r] + bv);
    }
  }
}

// ---------------------------------------------------------------------------
// Fused 2-layer persistent recurrence + heater. 512 blocks x 256 thr.
// Rec: blocks 0..127, wave 0 only. layer = blockIdx.x>>6, blk = blockIdx.x&63.
// All other waves: FMA heater spinning until done==128 (keeps GFXCLK up).
// ---------------------------------------------------------------------------
__global__ __launch_bounds__(256)
void lstm_fused(const bf16* __restrict__ wx, const bf16* __restrict__ Ub0,
                const bf16* __restrict__ Wb1, const bf16* __restrict__ Ub1,
                const float* __restrict__ ub0, const float* __restrict__ w1b,
                const float* __restrict__ u1b, float* __restrict__ out,
                u64* __restrict__ payl0, u64* __restrict__ payl1,
                unsigned int* __restrict__ flags0, unsigned int* __restrict__ flags1,
                unsigned int* __restrict__ done)
{
  __shared__ char lds[8 * STR1];     // L0 uses 8*STR0 of it
  const int wv = threadIdx.x >> 6;

  if (blockIdx.x >= N_REC_BLK || wv != 0) {
    // ---------------- heater ----------------
    float a0 = (float)threadIdx.x, a1 = a0 + 1.f, a2 = a0 + 2.f, a3 = a0 + 3.f;
    float a4 = a0 + 4.f, a5 = a0 + 5.f, a6 = a0 + 6.f, a7 = a0 + 7.f;
    const float xm = 1.0000001f, ya = 1e-7f;
    int g = 0;
    for (;;) {
      #pragma unroll
      for (int it = 0; it < 64; ++it) {
        asm volatile("v_fmac_f32 %0, %1, %2" : "+v"(a0) : "v"(xm), "v"(ya));
        asm volatile("v_fmac_f32 %0, %1, %2" : "+v"(a1) : "v"(xm), "v"(ya));
        asm volatile("v_fmac_f32 %0, %1, %2" : "+v"(a2) : "v"(xm), "v"(ya));
        asm volatile("v_fmac_f32 %0, %1, %2" : "+v"(a3) : "v"(xm), "v"(ya));
        asm volatile("v_fmac_f32 %0, %1, %2" : "+v"(a4) : "v"(xm), "v"(ya));
        asm volatile("v_fmac_f32 %0, %1, %2" : "+v"(a5) : "v"(xm), "v"(ya));
        asm volatile("v_fmac_f32 %0, %1, %2" : "+v"(a6) : "v"(xm), "v"(ya));
        asm volatile("v_fmac_f32 %0, %1, %2" : "+v"(a7) : "v"(xm), "v"(ya));
      }
      if (__hip_atomic_load(done, __ATOMIC_RELAXED,
                            __HIP_MEMORY_SCOPE_AGENT) >= 128u) break;
      if (++g > (1 << 20)) break;
    }
    return;
  }

  // ---------------- recurrence (wave 0 of blocks 0..127) ----------------
  asm volatile("s_setprio 3" ::: "memory");
  const int lane  = threadIdx.x;     // 0..63
  const int q     = lane >> 4;
  const int b     = lane & 15;
  const int layer = blockIdx.x >> 6;
  const int blk   = blockIdx.x & 63;
  const int jbase = blk * 8;
  const int jj    = jbase + (q & 1) * 4;

  const int row0 = (b < 8) ? (jbase + b) : (512 + jbase + b - 8);           // i | f
  const int row1 = (b < 8) ? (1024 + jbase + b) : (1536 + jbase + b - 8);   // g | o

  float* hh = out + ((layer == 0) ? HH_OFF : HH_OFF + 4096);
  float* cc = out + ((layer == 0) ? CC_OFF : CC_OFF + 4096);

  if (layer == 0) {
    // ---- Layer 0: K=512 (U0 * h1(t-1)) + precomputed wx ----
    short8 a0[16], a1[16];
    {
      const bf16* U0p = Ub0 + (long)row0 * 512 + q * 8;
      const bf16* U1p = Ub0 + (long)row1 * 512 + q * 8;
      #pragma unroll
      for (int kt = 0; kt < 16; ++kt) {
        a0[kt] = *reinterpret_cast<const short8*>(U0p + kt * 32);
        a1[kt] = *reinterpret_cast<const short8*>(U1p + kt * 32);
      }
    }
    float ubi[4], ubf[4], ubg[4], ubo[4];
    #pragma unroll
    for (int r = 0; r < 4; ++r) {
      ubi[r] = ub0[        jj + r];
      ubf[r] = ub0[ 512 + jj + r];
      ubg[r] = ub0[1024 + jj + r];
      ubo[r] = ub0[1536 + jj + r];
    }
    float cst[4] = {0.f, 0.f, 0.f, 0.f};

    for (int t = 0; t < T_STEPS; ++t) {
      const bf16* wxp = wx + (long)t * 16384 + (b & 7) * 2048 + jj;
      short4v vi = *reinterpret_cast<const short4v*>(wxp);
      short4v vf = *reinterpret_cast<const short4v*>(wxp + 512);
      short4v vg = *reinterpret_cast<const short4v*>(wxp + 1024);
      short4v vo = *reinterpret_cast<const short4v*>(wxp + 1536);

      floatx4 acc0 = {0.f, 0.f, 0.f, 0.f};
      floatx4 acc1 = {0.f, 0.f, 0.f, 0.f};

      if (t > 0) {
        // Poll 64 producer flags (1 load/lane, 2 lines total).
        const unsigned int* fl = flags0 + (long)(t - 1) * 64;
        int guard = 0;
        for (;;) {
          unsigned int f = __hip_atomic_load(fl + lane, __ATOMIC_RELAXED,
                                             __HIP_MEMORY_SCOPE_AGENT);
          if (__all(f != 0u)) break;
          if (++guard > GUARD_MAX) break;
        }
        __builtin_amdgcn_fence(__ATOMIC_ACQUIRE, "agent");
        fetch_payl(payl0 + (long)(t - 1) * 1024, lane, lds, STR0, 0);
        #pragma unroll
        for (int kt = 0; kt < 16; ++kt) {
          short8 hb = *reinterpret_cast<const short8*>(
              lds + (b & 7) * STR0 + kt * 64 + q * 16);
          acc0 = mfma_bf16(a0[kt], hb, acc0);
          acc1 = mfma_bf16(a1[kt], hb, acc1);
        }
      }

      float wxi[4], wxf[4], wxg[4], wxo[4];
      #pragma unroll
      for (int r = 0; r < 4; ++r) {
        wxi[r] = bs2f(vi[r]); wxf[r] = bs2f(vf[r]);
        wxg[r] = bs2f(vg[r]); wxo[r] = bs2f(vo[r]);
      }
      float fsh[4], osh[4];
      #pragma unroll
      for (int r = 0; r < 4; ++r) {
        fsh[r] = __shfl_xor(acc0[r], 32, 64);
        osh[r] = __shfl_xor(acc1[r], 32, 64);
      }

      if (q < 2 && b < 8) {
        short4v hp4; floatx4 hf4, cf4;
        #pragma unroll
        for (int r = 0; r < 4; ++r) {
          const float pi = acc0[r] + wxi[r] + ubi[r];
          const float pf = fsh[r]  + wxf[r] + ubf[r];
          const float pg = acc1[r] + wxg[r] + ubg[r];
          const float po = osh[r]  + wxo[r] + ubo[r];
          const float it = sigm(pi), ft = sigm(pf);
          const float gt = tanhf_(pg), ot = sigm(po);
          const float cv = ft * cst[r] + it * gt;
          cst[r] = cv;
          const float hv = ot * fmaxf(cv, 0.f);
          hf4[r] = hv; cf4[r] = cv; hp4[r] = f2bs(hv);
        }
        union { short4v v; u64 u; } pk; pk.v = hp4;
        cstore(payl0 + (long)t * 1024 + blk * 16 + (b * 2 + (q & 1)), pk.u);
        if (t == T_STEPS - 1) {
          *reinterpret_cast<floatx4*>(hh + b * 512 + jj) = hf4;
          *reinterpret_cast<floatx4*>(cc + b * 512 + jj) = cf4;
        }
      }
      // Release flag: s_waitcnt vmcnt(0) before this store orders the whole
      // wave's payload stores at agent scope.
      if (lane == 0) {
        __hip_atomic_store(flags0 + (long)t * 64 + blk, 1u, __ATOMIC_RELEASE,
                           __HIP_MEMORY_SCOPE_AGENT);
      }
    }
  } else {
    // ---- Layer 1: K=1024 ([W1|U1] * [h1(t); h2(t-1)]) ----
    short8 a0[32], a1[32];
    {
      const bf16* W0p = Wb1 + (long)row0 * 512 + q * 8;
      const bf16* W1p = Wb1 + (long)row1 * 512 + q * 8;
      const bf16* U0p = Ub1 + (long)row0 * 512 + q * 8;
      const bf16* U1p = Ub1 + (long)row1 * 512 + q * 8;
      #pragma unroll
      for (int kt = 0; kt < 16; ++kt) {
        a0[kt]      = *reinterpret_cast<const short8*>(W0p + kt * 32);
        a1[kt]      = *reinterpret_cast<const short8*>(W1p + kt * 32);
        a0[16 + kt] = *reinterpret_cast<const short8*>(U0p + kt * 32);
        a1[16 + kt] = *reinterpret_cast<const short8*>(U1p + kt * 32);
      }
    }
    float ubi[4], ubf[4], ubg[4], ubo[4];
    #pragma unroll
    for (int r = 0; r < 4; ++r) {
      ubi[r] = w1b[        jj + r] + u1b[        jj + r];
      ubf[r] = w1b[ 512 + jj + r] + u1b[ 512 + jj + r];
      ubg[r] = w1b[1024 + jj + r] + u1b[1024 + jj + r];
      ubo[r] = w1b[1536 + jj + r] + u1b[1536 + jj + r];
    }
    float cst[4] = {0.f, 0.f, 0.f, 0.f};

    for (int t = 0; t < T_STEPS; ++t) {
      floatx4 acc0 = {0.f, 0.f, 0.f, 0.f};
      floatx4 acc1 = {0.f, 0.f, 0.f, 0.f};

      if (t > 0) {
        const unsigned int* f0p = flags0 + (long)t * 64;
        const unsigned int* f1p = flags1 + (long)(t - 1) * 64;
        int guard = 0;
        for (;;) {
          unsigned int f = __hip_atomic_load(f0p + lane, __ATOMIC_RELAXED,
                                             __HIP_MEMORY_SCOPE_AGENT);
          unsigned int g = __hip_atomic_load(f1p + lane, __ATOMIC_RELAXED,
                                             __HIP_MEMORY_SCOPE_AGENT);
          if (__all(f != 0u && g != 0u)) break;
          if (++guard > GUARD_MAX) break;
        }
        __builtin_amdgcn_fence(__ATOMIC_ACQUIRE, "agent");
        fetch_payl(payl0 + (long)t * 1024,       lane, lds, STR1, 0);
        fetch_payl(payl1 + (long)(t - 1) * 1024, lane, lds, STR1, 1024);
      } else {
        const unsigned int* f0p = flags0;   // t = 0
        int guard = 0;
        for (;;) {
          unsigned int f = __hip_atomic_load(f0p + lane, __ATOMIC_RELAXED,
                                             __HIP_MEMORY_SCOPE_AGENT);
          if (__all(f != 0u)) break;
          if (++guard > GUARD_MAX) break;
        }
        __builtin_amdgcn_fence(__ATOMIC_ACQUIRE, "agent");
        fetch_payl(payl0, lane, lds, STR1, 0);
      }

      #pragma unroll
      for (int kt = 0; kt < 16; ++kt) {
        short8 hb = *reinterpret_cast<const short8*>(
            lds + (b & 7) * STR1 + kt * 64 + q * 16);
        acc0 = mfma_bf16(a0[kt], hb, acc0);
        acc1 = mfma_bf16(a1[kt], hb, acc1);
      }
      if (t > 0) {
        #pragma unroll
        for (int kt = 16; kt < 32; ++kt) {
          short8 hb = *reinterpret_cast<const short8*>(
              lds + (b & 7) * STR1 + kt * 64 + q * 16);
          acc0 = mfma_bf16(a0[kt], hb, acc0);
          acc1 = mfma_bf16(a1[kt], hb, acc1);
        }
      }

      float fsh[4], osh[4];
      #pragma unroll
      for (int r = 0; r < 4; ++r) {
        fsh[r] = __shfl_xor(acc0[r], 32, 64);
        osh[r] = __shfl_xor(acc1[r], 32, 64);
      }

      if (q < 2 && b < 8) {
        short4v hp4; floatx4 hf4, cf4;
        #pragma unroll
        for (int r = 0; r < 4; ++r) {
          const float pi = acc0[r] + ubi[r];
          const float pf = fsh[r]  + ubf[r];
          const float pg = acc1[r] + ubg[r];
          const float po = osh[r]  + ubo[r];
          const float it = sigm(pi), ft = sigm(pf);
          const float gt = tanhf_(pg), ot = sigm(po);
          const float cv = ft * cst[r] + it * gt;
          cst[r] = cv;
          const float hv = ot * fmaxf(cv, 0.f);
          hf4[r] = hv; cf4[r] = cv; hp4[r] = f2bs(hv);
        }
        union { short4v v; u64 u; } pk; pk.v = hp4;
        cstore(payl1 + (long)t * 1024 + blk * 16 + (b * 2 + (q & 1)), pk.u);
        *reinterpret_cast<floatx4*>(out + (long)b * 1048576 + (long)t * 512 + jj) = hf4;
        if (t == T_STEPS - 1) {
          *reinterpret_cast<floatx4*>(hh + b * 512 + jj) = hf4;
          *reinterpret_cast<floatx4*>(cc + b * 512 + jj) = cf4;
        }
      }
      if (lane == 0) {
        __hip_atomic_store(flags1 + (long)t * 64 + blk, 1u, __ATOMIC_RELEASE,
                           __HIP_MEMORY_SCOPE_AGENT);
      }
    }
  }

  // Signal heaters to exit.
  if (lane == 0) {
    __hip_atomic_fetch_add(done, 1u, __ATOMIC_RELAXED, __HIP_MEMORY_SCOPE_AGENT);
  }
}

extern "C" void kernel_launch(void* const* d_in, const int* in_sizes, int n_in,
                              void* d_out, int out_size, void* d_ws, size_t ws_size,
                              hipStream_t stream) {
  (void)in_sizes; (void)n_in; (void)out_size; (void)ws_size;
  const float* x   = (const float*)d_in[0];
  const float* w0w = (const float*)d_in[1];
  const float* w0b = (const float*)d_in[2];
  const float* u0w = (const float*)d_in[3];
  const float* u0b = (const float*)d_in[4];
  const float* w1w = (const float*)d_in[5];
  const float* w1b = (const float*)d_in[6];
  const float* u1w = (const float*)d_in[7];
  const float* u1b = (const float*)d_in[8];
  float* out = (float*)d_out;

  char* ws = (char*)d_ws;
  u64*  payl0 = (u64*)ws;
  u64*  payl1 = (u64*)(ws + (size_t)16777216);
  bf16* Wb0 = (bf16*)(ws + (size_t)33554432);
  bf16* Ub0 = (bf16*)(ws + (size_t)34603008);
  bf16* Wb1 = (bf16*)(ws + (size_t)36700160);
  bf16* Ub1 = (bf16*)(ws + (size_t)38797312);
  bf16* wx  = (bf16*)(ws + (size_t)40894464);
  unsigned int* flags0 = (unsigned int*)(ws + (size_t)108003328);
  unsigned int* flags1 = (unsigned int*)(ws + (size_t)108527616);
  unsigned int* done   = (unsigned int*)(ws + (size_t)115343360);

  // Zero flags + done counter (payload no longer needs sentinel fill).
  hipMemsetAsync(ws + (size_t)108003328, 0, (size_t)1048576, stream);
  hipMemsetAsync(done, 0, 64, stream);

  // Weight conversions fp32 -> bf16.
  cvt_f32_bf16<<<512,  256, 0, stream>>>(w0w, Wb0, 524288);
  cvt_f32_bf16<<<1024, 256, 0, stream>>>(u0w, Ub0, 1048576);
  cvt_f32_bf16<<<1024, 256, 0, stream>>>(w1w, Wb1, 1048576);
  cvt_f32_bf16<<<1024, 256, 0, stream>>>(u1w, Ub1, 1048576);

  // Layer-0 input projection.
  dim3 gg(1024, 8, 1);
  gemm_proj<<<gg, 256, 0, stream>>>(x, Wb0, w0b, wx, 256, 2048 * 256, 256);

  // Fused 2-layer recurrence + heaters.
  lstm_fused<<<N_BLK, 256, 0, stream>>>(wx, Ub0, Wb1, Ub1, u0b, w1b, u1b,
                                        out, payl0, payl1, flags0, flags1, done);
}

// Round 3
// 9042.657 us; speedup vs baseline: 2.8939x; 1.5496x over previous
//
#include <hip/hip_runtime.h>
#include <hip/hip_bf16.h>
#include <stdint.h>

// LSTM_48601849922171 — 2-layer LSTM (B=8, T=2048, D_IN=256, H=512), fp32 I/O,
// bf16 MFMA compute.
//
// Round 10: XCD-clustered recurrence, no VGPR cap (R8's failure was the
// __launch_bounds__(256,2) 128-VGPR cap spilling L1 weights; its XCC_ID
// ticket-claim + sc0/agent-fallback protocol PASSED). R9 proved the per-step
// floor is the agent-scope visibility chain (flag protocol added a round trip
// and got slower; FETCH unchanged), so: shrink the coherence domain to one
// XCD's L2.
//   - 512 blocks x 256 thr (all co-resident: 208 VGPR => 2 waves/SIMD,
//     17+17KB LDS dbuf => 2 blocks/CU). Blocks on XCD0 claim 32 tickets.
//   - Ticket = (layer = tk>>4, grp = tk&15); block's 4 waves handle
//     blk = grp*4 + wv (same per-wave code/registers as R7's 128 blocks).
//   - Exchange: data-as-sentinel (NO flag round trip). Producer: plain
//     global_store (write-through L1 -> XCD0 L2) + same-value agent shadow
//     store (MALL) for the fallback path. Consumer: sc0 poll loads (bypass
//     L1, hit shared L2, ~200cy) with an agent-scope sweep every 16th iter
//     (breaks stale-L2 if clustering assumption ever fails; guard-capped).
//   - Block's 4 waves share the staged h in LDS: each wave polls+fetches a
//     2KB quarter (2x dwordx4/lane, coalesced), writes 2x16B LDS rows,
//     one __syncthreads, all MFMA from shared buffer (double-buffered).
//   - wx prefetched one step ahead (HBM latency off the critical path).
//
// Workspace (~111 MB):
//   0:        payl0 [2048][64][16] u64 = 16 MB  (memset 0xFF)
//   16M:      payl1 16 MB                        (memset 0xFF)
//   32M:      Wb0 1MB | 33M: Ub0 2MB | 35M: Wb1 2MB | 37M: Ub1 2MB
//   39M:      wx0 [2048][8][2048] bf16 = 64 MB
//   115343360: done u32, claim u32 (memset 0)

typedef __hip_bfloat16 bf16;
typedef float  floatx4 __attribute__((ext_vector_type(4)));
typedef short  short8  __attribute__((ext_vector_type(8)));
typedef short  short4v __attribute__((ext_vector_type(4)));
typedef unsigned int u32x4 __attribute__((ext_vector_type(4)));
typedef unsigned long long u64;

#define T_STEPS  2048
#define SENT32   0xFFFFFFFFu
#define HH_OFF   8388608   // 8*2048*512
#define CC_OFF   8396800   // HH_OFF + 2*8*512
#define STR0     1056      // LDS row stride bytes, layer 0 ([8][512+pad])
#define STR1     2080      // LDS row stride bytes, layer 1 ([8][1024+pad])
#define BUFSZ    16640     // 8*STR1, one staging buffer slot
#define N_BLK    512
#define N_TICK   32
#define GUARD_MAX (1 << 18)

static __device__ __forceinline__ float bs2f(short s) {
  union { unsigned int u; float f; } c;
  c.u = ((unsigned int)(unsigned short)s) << 16;
  return c.f;
}
static __device__ __forceinline__ short f2bs(float x) {
  union { bf16 h; short s; } u;
  u.h = __float2bfloat16(x);
  return u.s;
}
static __device__ __forceinline__ float sigm(float x) {
  x = fminf(fmaxf(x, -30.f), 30.f);
  return 1.f / (1.f + __expf(-x));
}
static __device__ __forceinline__ float tanhf_(float x) {
  x = fminf(fmaxf(x, -15.f), 15.f);
  float e = __expf(2.f * x);
  return (e - 1.f) / (e + 1.f);
}
static __device__ __forceinline__ floatx4 mfma_bf16(short8 a, short8 b, floatx4 c) {
  return __builtin_amdgcn_mfma_f32_16x16x32_bf16(a, b, c, 0, 0, 0);
}
static __device__ __forceinline__ u64 cload(const u64* p) {
  return __hip_atomic_load(p, __ATOMIC_RELAXED, __HIP_MEMORY_SCOPE_AGENT);
}
static __device__ __forceinline__ void cstore(u64* p, u64 v) {
  __hip_atomic_store(p, v, __ATOMIC_RELAXED, __HIP_MEMORY_SCOPE_AGENT);
}
// Plain store: write-through L1 into the XCD-local L2.
static __device__ __forceinline__ void stg64(u64* p, u64 v) {
  asm volatile("global_store_dwordx2 %0, %1, off" :: "v"(p), "v"(v) : "memory");
}
// 32B sc0 load (bypass L1, served by XCD-local L2 when line is dirty there).
static __device__ __forceinline__ void ld32_sc0(const u64* p, u32x4& A, u32x4& B) {
  asm volatile("global_load_dwordx4 %0, %2, off sc0\n\t"
               "global_load_dwordx4 %1, %2, off offset:16 sc0\n\t"
               "s_waitcnt vmcnt(0)"
               : "=v"(A), "=v"(B) : "v"(p) : "memory");
}
// Agent-scope (MALL) fallback, same addresses.
static __device__ __forceinline__ void ld32_agent(const u64* p, u32x4& A, u32x4& B) {
  u64 q0 = cload(p), q1 = cload(p + 1), q2 = cload(p + 2), q3 = cload(p + 3);
  A.x = (unsigned)q0; A.y = (unsigned)(q0 >> 32);
  A.z = (unsigned)q1; A.w = (unsigned)(q1 >> 32);
  B.x = (unsigned)q2; B.y = (unsigned)(q2 >> 32);
  B.z = (unsigned)q3; B.w = (unsigned)(q3 >> 32);
}
// Valid payload u32 is never all-ones (h >= 0 => bf16 sign bits are 0).
static __device__ __forceinline__ int valid2(const u32x4& A, const u32x4& B) {
  int ok = 1;
  ok &= (A.x != SENT32); ok &= (A.y != SENT32);
  ok &= (A.z != SENT32); ok &= (A.w != SENT32);
  ok &= (B.x != SENT32); ok &= (B.y != SENT32);
  ok &= (B.z != SENT32); ok &= (B.w != SENT32);
  return ok;
}
// Per-wave quarter poll+fetch of one 8KB payload into the shared LDS image.
// Payload u64 idx p = wv*256 + lane*4 + i -> LDS row ((p&15)>>1),
// byte col (p>>4)*16 + (p&1)*8 (verified mapping from R7 layout algebra).
static __device__ __forceinline__ void poll_fetch_q(const u64* paylT, int wv,
                                                    int lane, char* buf,
                                                    int stride, int colOff) {
  const u64* p = paylT + wv * 256 + lane * 4;
  u32x4 A, B;
  int guard = 0;
  for (;;) {
    if ((guard & 15) == 15) ld32_agent(p, A, B);
    else                    ld32_sc0(p, A, B);
    if (__all(valid2(A, B))) break;
    if (++guard > GUARD_MAX) break;
  }
  char* base = buf + colOff + wv * 256 + (lane >> 2) * 16;
  const int r0 = (lane & 3) * 2;
  *reinterpret_cast<u32x4*>(base + (long)r0 * stride)       = A;
  *reinterpret_cast<u32x4*>(base + (long)(r0 + 1) * stride) = B;
}

// fp32 -> bf16 elementwise (n multiple of 4)
__global__ __launch_bounds__(256)
void cvt_f32_bf16(const float* __restrict__ src, bf16* __restrict__ dst, int n) {
  int i = (blockIdx.x * 256 + threadIdx.x) * 4;
  if (i < n) {
    floatx4 v = *reinterpret_cast<const floatx4*>(src + i);
    short4v o;
    #pragma unroll
    for (int r = 0; r < 4; ++r) o[r] = f2bs(v[r]);
    *reinterpret_cast<short4v*>(dst + i) = o;
  }
}

// ---------------------------------------------------------------------------
// Layer-0 input projection (unchanged from R7).
// ---------------------------------------------------------------------------
__global__ __launch_bounds__(256)
void gemm_proj(const float* __restrict__ Af, const bf16* __restrict__ W,
               const float* __restrict__ bias, bf16* __restrict__ out,
               int K, int strideB, int strideT)
{
  const int lane  = threadIdx.x & 63;
  const int wave  = threadIdx.x >> 6;
  const int q     = lane >> 4;
  const int c     = lane & 15;
  const int mtile = blockIdx.x;
  const int nbase = blockIdx.y * 256 + wave * 64;
  const int m     = mtile * 16 + c;

  const long abase = (long)(m & 7) * strideB + (long)(m >> 3) * strideT + q * 8;
  const bf16* W0 = W + (long)(nbase +  0 + c) * K + q * 8;
  const bf16* W1 = W + (long)(nbase + 16 + c) * K + q * 8;
  const bf16* W2 = W + (long)(nbase + 32 + c) * K + q * 8;
  const bf16* W3 = W + (long)(nbase + 48 + c) * K + q * 8;

  floatx4 acc0 = {0.f, 0.f, 0.f, 0.f};
  floatx4 acc1 = acc0, acc2 = acc0, acc3 = acc0;
  const int nk = K >> 5;
  for (int kt = 0; kt < nk; ++kt) {
    short8 a;
    floatx4 lo = *reinterpret_cast<const floatx4*>(Af + abase + kt * 32);
    floatx4 hi = *reinterpret_cast<const floatx4*>(Af + abase + kt * 32 + 4);
    #pragma unroll
    for (int r = 0; r < 4; ++r) { a[r] = f2bs(lo[r]); a[4 + r] = f2bs(hi[r]); }
    short8 b0 = *reinterpret_cast<const short8*>(W0 + kt * 32);
    short8 b1 = *reinterpret_cast<const short8*>(W1 + kt * 32);
    short8 b2 = *reinterpret_cast<const short8*>(W2 + kt * 32);
    short8 b3 = *reinterpret_cast<const short8*>(W3 + kt * 32);
    acc0 = mfma_bf16(a, b0, acc0);
    acc1 = mfma_bf16(a, b1, acc1);
    acc2 = mfma_bf16(a, b2, acc2);
    acc3 = mfma_bf16(a, b3, acc3);
  }

  floatx4 accs[4] = {acc0, acc1, acc2, acc3};
  #pragma unroll
  for (int nt = 0; nt < 4; ++nt) {
    const int n = nbase + nt * 16 + c;
    const float bv = bias[n];
    #pragma unroll
    for (int r = 0; r < 4; ++r) {
      const int mrow = mtile * 16 + q * 4 + r;
      out[(long)mrow * 2048 + n] = __float2bfloat16(accs[nt][r] + bv);
    }
  }
}

// ---------------------------------------------------------------------------
// Fused 2-layer persistent recurrence, XCD0-clustered. 512 blocks x 256 thr.
// ---------------------------------------------------------------------------
__global__ __launch_bounds__(256)
void lstm_fused(const bf16* __restrict__ wx, const bf16* __restrict__ Ub0,
                const bf16* __restrict__ Wb1, const bf16* __restrict__ Ub1,
                const float* __restrict__ ub0, const float* __restrict__ w1b,
                const float* __restrict__ u1b, float* __restrict__ out,
                u64* __restrict__ payl0, u64* __restrict__ payl1,
                unsigned int* __restrict__ done, unsigned int* __restrict__ claim)
{
  __shared__ char lds[2 * BUFSZ];   // double-buffered shared h staging
  __shared__ int s_ticket;
  if (threadIdx.x == 0) {
    int xcd = 0;
    asm volatile("s_getreg_b32 %0, hwreg(HW_REG_XCC_ID)" : "=s"(xcd));
    int tk = -1;
    if ((xcd & 7) == 0) {
      unsigned int t = __hip_atomic_fetch_add(claim, 1u, __ATOMIC_RELAXED,
                                              __HIP_MEMORY_SCOPE_AGENT);
      if (t < (unsigned)N_TICK) tk = (int)t;
    }
    s_ticket = tk;
  }
  __syncthreads();
  const int ticket = s_ticket;

  if (ticket < 0) {
    // ---------------- heater (all non-claimed blocks) ----------------
    float a0 = (float)threadIdx.x, a1 = a0 + 1.f, a2 = a0 + 2.f, a3 = a0 + 3.f;
    float a4 = a0 + 4.f, a5 = a0 + 5.f, a6 = a0 + 6.f, a7 = a0 + 7.f;
    const float xm = 1.0000001f, ya = 1e-7f;
    int g = 0;
    for (;;) {
      #pragma unroll
      for (int it = 0; it < 64; ++it) {
        asm volatile("v_fmac_f32 %0, %1, %2" : "+v"(a0) : "v"(xm), "v"(ya));
        asm volatile("v_fmac_f32 %0, %1, %2" : "+v"(a1) : "v"(xm), "v"(ya));
        asm volatile("v_fmac_f32 %0, %1, %2" : "+v"(a2) : "v"(xm), "v"(ya));
        asm volatile("v_fmac_f32 %0, %1, %2" : "+v"(a3) : "v"(xm), "v"(ya));
        asm volatile("v_fmac_f32 %0, %1, %2" : "+v"(a4) : "v"(xm), "v"(ya));
        asm volatile("v_fmac_f32 %0, %1, %2" : "+v"(a5) : "v"(xm), "v"(ya));
        asm volatile("v_fmac_f32 %0, %1, %2" : "+v"(a6) : "v"(xm), "v"(ya));
        asm volatile("v_fmac_f32 %0, %1, %2" : "+v"(a7) : "v"(xm), "v"(ya));
      }
      if (__hip_atomic_load(done, __ATOMIC_RELAXED,
                            __HIP_MEMORY_SCOPE_AGENT) >= (unsigned)N_TICK) break;
      if (++g > (1 << 20)) break;
    }
    return;
  }

  // ---------------- recurrence (4 waves of the 32 claimed blocks) ----------
  asm volatile("s_setprio 3" ::: "memory");
  const int wv    = threadIdx.x >> 6;
  const int lane  = threadIdx.x & 63;
  const int q     = lane >> 4;
  const int b     = lane & 15;
  const int layer = ticket >> 4;          // 0..1
  const int grp   = ticket & 15;          // 0..15
  const int blk   = grp * 4 + wv;         // 0..63
  const int jbase = blk * 8;
  const int jj    = jbase + (q & 1) * 4;

  const int row0 = (b < 8) ? (jbase + b) : (512 + jbase + b - 8);           // i | f
  const int row1 = (b < 8) ? (1024 + jbase + b) : (1536 + jbase + b - 8);   // g | o

  float* hh = out + ((layer == 0) ? HH_OFF : HH_OFF + 4096);
  float* cc = out + ((layer == 0) ? CC_OFF : CC_OFF + 4096);

  if (layer == 0) {
    // ---- Layer 0: K=512 (U0 * h1(t-1)) + precomputed wx ----
    short8 a0[16], a1[16];
    {
      const bf16* U0p = Ub0 + (long)row0 * 512 + q * 8;
      const bf16* U1p = Ub0 + (long)row1 * 512 + q * 8;
      #pragma unroll
      for (int kt = 0; kt < 16; ++kt) {
        a0[kt] = *reinterpret_cast<const short8*>(U0p + kt * 32);
        a1[kt] = *reinterpret_cast<const short8*>(U1p + kt * 32);
      }
    }
    float ubi[4], ubf[4], ubg[4], ubo[4];
    #pragma unroll
    for (int r = 0; r < 4; ++r) {
      ubi[r] = ub0[        jj + r];
      ubf[r] = ub0[ 512 + jj + r];
      ubg[r] = ub0[1024 + jj + r];
      ubo[r] = ub0[1536 + jj + r];
    }
    float cst[4] = {0.f, 0.f, 0.f, 0.f};

    // wx prefetch pipeline: regs hold step t while loop body issues t+1.
    const bf16* wxbase = wx + (b & 7) * 2048 + jj;
    short4v vi = *reinterpret_cast<const short4v*>(wxbase);
    short4v vf = *reinterpret_cast<const short4v*>(wxbase + 512);
    short4v vg = *reinterpret_cast<const short4v*>(wxbase + 1024);
    short4v vo = *reinterpret_cast<const short4v*>(wxbase + 1536);

    for (int t = 0; t < T_STEPS; ++t) {
      float wxi[4], wxf[4], wxg[4], wxo[4];
      #pragma unroll
      for (int r = 0; r < 4; ++r) {
        wxi[r] = bs2f(vi[r]); wxf[r] = bs2f(vf[r]);
        wxg[r] = bs2f(vg[r]); wxo[r] = bs2f(vo[r]);
      }
      if (t + 1 < T_STEPS) {
        const bf16* wn = wxbase + (long)(t + 1) * 16384;
        vi = *reinterpret_cast<const short4v*>(wn);
        vf = *reinterpret_cast<const short4v*>(wn + 512);
        vg = *reinterpret_cast<const short4v*>(wn + 1024);
        vo = *reinterpret_cast<const short4v*>(wn + 1536);
      }

      char* buf = lds + (t & 1) * BUFSZ;
      floatx4 acc0 = {0.f, 0.f, 0.f, 0.f};
      floatx4 acc1 = {0.f, 0.f, 0.f, 0.f};

      if (t > 0)
        poll_fetch_q(payl0 + (long)(t - 1) * 1024, wv, lane, buf, STR0, 0);
      __syncthreads();
      if (t > 0) {
        #pragma unroll
        for (int kt = 0; kt < 16; ++kt) {
          short8 hb = *reinterpret_cast<const short8*>(
              buf + (b & 7) * STR0 + kt * 64 + q * 16);
          acc0 = mfma_bf16(a0[kt], hb, acc0);
          acc1 = mfma_bf16(a1[kt], hb, acc1);
        }
      }

      float fsh[4], osh[4];
      #pragma unroll
      for (int r = 0; r < 4; ++r) {
        fsh[r] = __shfl_xor(acc0[r], 32, 64);
        osh[r] = __shfl_xor(acc1[r], 32, 64);
      }

      if (q < 2 && b < 8) {
        short4v hp4; floatx4 hf4, cf4;
        #pragma unroll
        for (int r = 0; r < 4; ++r) {
          const float pi = acc0[r] + wxi[r] + ubi[r];
          const float pf = fsh[r]  + wxf[r] + ubf[r];
          const float pg = acc1[r] + wxg[r] + ubg[r];
          const float po = osh[r]  + wxo[r] + ubo[r];
          const float it = sigm(pi), ft = sigm(pf);
          const float gt = tanhf_(pg), ot = sigm(po);
          const float cv = ft * cst[r] + it * gt;
          cst[r] = cv;
          const float hv = ot * fmaxf(cv, 0.f);
          hf4[r] = hv; cf4[r] = cv; hp4[r] = f2bs(hv);
        }
        union { short4v v; u64 u; } pk; pk.v = hp4;
        u64* dst = payl0 + (long)t * 1024 + blk * 16 + (b * 2 + (q & 1));
        stg64(dst, pk.u);     // fast path: XCD0 L2
        cstore(dst, pk.u);    // shadow: MALL (fallback readers)
        if (t == T_STEPS - 1) {
          *reinterpret_cast<floatx4*>(hh + b * 512 + jj) = hf4;
          *reinterpret_cast<floatx4*>(cc + b * 512 + jj) = cf4;
        }
      }
    }
  } else {
    // ---- Layer 1: K=1024 ([W1|U1] * [h1(t); h2(t-1)]) ----
    short8 a0[32], a1[32];
    {
      const bf16* W0p = Wb1 + (long)row0 * 512 + q * 8;
      const bf16* W1p = Wb1 + (long)row1 * 512 + q * 8;
      const bf16* U0p = Ub1 + (long)row0 * 512 + q * 8;
      const bf16* U1p = Ub1 + (long)row1 * 512 + q * 8;
      #pragma unroll
      for (int kt = 0; kt < 16; ++kt) {
        a0[kt]      = *reinterpret_cast<const short8*>(W0p + kt * 32);
        a1[kt]      = *reinterpret_cast<const short8*>(W1p + kt * 32);
        a0[16 + kt] = *reinterpret_cast<const short8*>(U0p + kt * 32);
        a1[16 + kt] = *reinterpret_cast<const short8*>(U1p + kt * 32);
      }
    }
    float ubi[4], ubf[4], ubg[4], ubo[4];
    #pragma unroll
    for (int r = 0; r < 4; ++r) {
      ubi[r] = w1b[        jj + r] + u1b[        jj + r];
      ubf[r] = w1b[ 512 + jj + r] + u1b[ 512 + jj + r];
      ubg[r] = w1b[1024 + jj + r] + u1b[1024 + jj + r];
      ubo[r] = w1b[1536 + jj + r] + u1b[1536 + jj + r];
    }
    float cst[4] = {0.f, 0.f, 0.f, 0.f};

    for (int t = 0; t < T_STEPS; ++t) {
      char* buf = lds + (t & 1) * BUFSZ;
      floatx4 acc0 = {0.f, 0.f, 0.f, 0.f};
      floatx4 acc1 = {0.f, 0.f, 0.f, 0.f};

      if (t > 0) {
        poll_fetch_q(payl0 + (long)t * 1024,       wv, lane, buf, STR1, 0);
        poll_fetch_q(payl1 + (long)(t - 1) * 1024, wv, lane, buf, STR1, 1024);
      } else {
        poll_fetch_q(payl0, wv, lane, buf, STR1, 0);
      }
      __syncthreads();

      #pragma unroll
      for (int kt = 0; kt < 16; ++kt) {
        short8 hb = *reinterpret_cast<const short8*>(
            buf + (b & 7) * STR1 + kt * 64 + q * 16);
        acc0 = mfma_bf16(a0[kt], hb, acc0);
        acc1 = mfma_bf16(a1[kt], hb, acc1);
      }
      if (t > 0) {
        #pragma unroll
        for (int kt = 16; kt < 32; ++kt) {
          short8 hb = *reinterpret_cast<const short8*>(
              buf + (b & 7) * STR1 + kt * 64 + q * 16);
          acc0 = mfma_bf16(a0[kt], hb, acc0);
          acc1 = mfma_bf16(a1[kt], hb, acc1);
        }
      }

      float fsh[4], osh[4];
      #pragma unroll
      for (int r = 0; r < 4; ++r) {
        fsh[r] = __shfl_xor(acc0[r], 32, 64);
        osh[r] = __shfl_xor(acc1[r], 32, 64);
      }

      if (q < 2 && b < 8) {
        short4v hp4; floatx4 hf4, cf4;
        #pragma unroll
        for (int r = 0; r < 4; ++r) {
          const float pi = acc0[r] + ubi[r];
          const float pf = fsh[r]  + ubf[r];
          const float pg = acc1[r] + ubg[r];
          const float po = osh[r]  + ubo[r];
          const float it = sigm(pi), ft = sigm(pf);
          const float gt = tanhf_(pg), ot = sigm(po);
          const float cv = ft * cst[r] + it * gt;
          cst[r] = cv;
          const float hv = ot * fmaxf(cv, 0.f);
          hf4[r] = hv; cf4[r] = cv; hp4[r] = f2bs(hv);
        }
        union { short4v v; u64 u; } pk; pk.v = hp4;
        u64* dst = payl1 + (long)t * 1024 + blk * 16 + (b * 2 + (q & 1));
        stg64(dst, pk.u);     // fast path: XCD0 L2
        cstore(dst, pk.u);    // shadow: MALL (fallback readers)
        *reinterpret_cast<floatx4*>(out + (long)b * 1048576 + (long)t * 512 + jj) = hf4;
        if (t == T_STEPS - 1) {
          *reinterpret_cast<floatx4*>(hh + b * 512 + jj) = hf4;
          *reinterpret_cast<floatx4*>(cc + b * 512 + jj) = cf4;
        }
      }
    }
  }

  // Signal heaters to exit (one per rec block).
  __syncthreads();
  if (threadIdx.x == 0) {
    __hip_atomic_fetch_add(done, 1u, __ATOMIC_RELAXED, __HIP_MEMORY_SCOPE_AGENT);
  }
}

extern "C" void kernel_launch(void* const* d_in, const int* in_sizes, int n_in,
                              void* d_out, int out_size, void* d_ws, size_t ws_size,
                              hipStream_t stream) {
  (void)in_sizes; (void)n_in; (void)out_size; (void)ws_size;
  const float* x   = (const float*)d_in[0];
  const float* w0w = (const float*)d_in[1];
  const float* w0b = (const float*)d_in[2];
  const float* u0w = (const float*)d_in[3];
  const float* u0b = (const float*)d_in[4];
  const float* w1w = (const float*)d_in[5];
  const float* w1b = (const float*)d_in[6];
  const float* u1w = (const float*)d_in[7];
  const float* u1b = (const float*)d_in[8];
  float* out = (float*)d_out;

  char* ws = (char*)d_ws;
  u64*  payl0 = (u64*)ws;
  u64*  payl1 = (u64*)(ws + (size_t)16777216);
  bf16* Wb0 = (bf16*)(ws + (size_t)33554432);
  bf16* Ub0 = (bf16*)(ws + (size_t)34603008);
  bf16* Wb1 = (bf16*)(ws + (size_t)36700160);
  bf16* Ub1 = (bf16*)(ws + (size_t)38797312);
  bf16* wx  = (bf16*)(ws + (size_t)40894464);
  unsigned int* done = (unsigned int*)(ws + (size_t)115343360);

  // Sentinel-fill payload arrays; zero the done+claim counters.
  hipMemsetAsync(ws, 0xFF, (size_t)33554432, stream);
  hipMemsetAsync(done, 0, 64, stream);

  // Weight conversions fp32 -> bf16.
  cvt_f32_bf16<<<512,  256, 0, stream>>>(w0w, Wb0, 524288);
  cvt_f32_bf16<<<1024, 256, 0, stream>>>(u0w, Ub0, 1048576);
  cvt_f32_bf16<<<1024, 256, 0, stream>>>(w1w, Wb1, 1048576);
  cvt_f32_bf16<<<1024, 256, 0, stream>>>(u1w, Ub1, 1048576);

  // Layer-0 input projection.
  dim3 gg(1024, 8, 1);
  gemm_proj<<<gg, 256, 0, stream>>>(x, Wb0, w0b, wx, 256, 2048 * 256, 256);

  // Fused 2-layer recurrence (XCD0-clustered) + heaters.
  lstm_fused<<<N_BLK, 256, 0, stream>>>(wx, Ub0, Wb1, Ub1, u0b, w1b, u1b,
                                        out, payl0, payl1, done, done + 1);
}

// Round 5
// 7097.293 us; speedup vs baseline: 3.6871x; 1.2741x over previous
//
#include <hip/hip_runtime.h>
#include <hip/hip_bf16.h>
#include <stdint.h>

// LSTM_48601849922171 — 2-layer LSTM (B=8, T=2048, D_IN=256, H=512), fp32 I/O,
// bf16 MFMA compute.
//
// Round 12: R10 structure + PURE agent-scope channel.
// R11's correctness failure proved plain-store + sc0-load is not a working
// producer->consumer channel on gfx950 (stores not promptly observable /
// stale L2 lines never invalidated; consumers spun to guard cap). R10 was
// correct only because of its agent shadow store — i.e. visibility ALWAYS
// flowed through the MALL. Its sc0 "fast path" just added a 16-poll
// detection granularity. So:
//   - Producer: single agent relaxed store (R7's proven semantics).
//   - Consumer: agent relaxed loads EVERY poll iteration (4x8B per lane,
//     coalesced, one MALL RT per round) — detection = 1-2 MALL RTs.
//   - L1: one fused spin over payl0[t] + payl1[t-1] (8 loads, 1 wait).
//   - Heater polls `done` every 32 outer iters (~14us) to keep that MALL
//     line quiet.
// Structure retained from R10 (verified): XCD0 ticket claim, 32 rec blocks
// x 4 waves with shared double-buffered LDS staging, coalesced quarter
// fetch (payload u64 idx p = wv*256+lane*4+i -> LDS row ((p&15)>>1), byte
// col (p>>4)*16+(p&1)*8), wx one-step register prefetch.
//
// Workspace (~111 MB):
//   0:        payl0 [2048][64][16] u64 = 16 MB  (memset 0xFF)
//   16M:      payl1 16 MB                        (memset 0xFF)
//   32M:      Wb0 1MB | 33M: Ub0 2MB | 35M: Wb1 2MB | 37M: Ub1 2MB
//   39M:      wx0 [2048][8][2048] bf16 = 64 MB
//   115343360: done u32, claim u32 (memset 0)

typedef __hip_bfloat16 bf16;
typedef float  floatx4 __attribute__((ext_vector_type(4)));
typedef short  short8  __attribute__((ext_vector_type(8)));
typedef short  short4v __attribute__((ext_vector_type(4)));
typedef unsigned long long u64;

#define T_STEPS  2048
#define SENT64   0xFFFFFFFFFFFFFFFFull
#define HH_OFF   8388608   // 8*2048*512
#define CC_OFF   8396800   // HH_OFF + 2*8*512
#define STR0     1056      // LDS row stride bytes, layer 0 ([8][512+pad])
#define STR1     2080      // LDS row stride bytes, layer 1 ([8][1024+pad])
#define BUFSZ    16640     // 8*STR1, one staging buffer slot
#define N_BLK    512
#define N_TICK   32
#define GUARD_MAX (1 << 18)

static __device__ __forceinline__ float bs2f(short s) {
  union { unsigned int u; float f; } c;
  c.u = ((unsigned int)(unsigned short)s) << 16;
  return c.f;
}
static __device__ __forceinline__ short f2bs(float x) {
  union { bf16 h; short s; } u;
  u.h = __float2bfloat16(x);
  return u.s;
}
static __device__ __forceinline__ float sigm(float x) {
  x = fminf(fmaxf(x, -30.f), 30.f);
  return 1.f / (1.f + __expf(-x));
}
static __device__ __forceinline__ float tanhf_(float x) {
  x = fminf(fmaxf(x, -15.f), 15.f);
  float e = __expf(2.f * x);
  return (e - 1.f) / (e + 1.f);
}
static __device__ __forceinline__ floatx4 mfma_bf16(short8 a, short8 b, floatx4 c) {
  return __builtin_amdgcn_mfma_f32_16x16x32_bf16(a, b, c, 0, 0, 0);
}
static __device__ __forceinline__ u64 cload(const u64* p) {
  return __hip_atomic_load(p, __ATOMIC_RELAXED, __HIP_MEMORY_SCOPE_AGENT);
}
static __device__ __forceinline__ void cstore(u64* p, u64 v) {
  __hip_atomic_store(p, v, __ATOMIC_RELAXED, __HIP_MEMORY_SCOPE_AGENT);
}

// Per-wave quarter poll+fetch of one 8KB payload into the shared LDS image.
// Agent loads every iteration (MALL-coherent; R7-proven semantics).
static __device__ __forceinline__ void poll_fetch_q(const u64* paylT, int wv,
                                                    int lane, char* buf,
                                                    int stride, int colOff) {
  const u64* p = paylT + wv * 256 + lane * 4;
  u64 q0, q1, q2, q3;
  int guard = 0;
  for (;;) {
    q0 = cload(p);     q1 = cload(p + 1);
    q2 = cload(p + 2); q3 = cload(p + 3);
    int ok = (q0 != SENT64) & (q1 != SENT64) & (q2 != SENT64) & (q3 != SENT64);
    if (__all(ok)) break;
    if (++guard > GUARD_MAX) break;
  }
  char* base = buf + colOff + wv * 256 + (lane >> 2) * 16;
  const int r0 = (lane & 3) * 2;
  *reinterpret_cast<u64*>(base + (long)r0 * stride)           = q0;
  *reinterpret_cast<u64*>(base + (long)r0 * stride + 8)       = q1;
  *reinterpret_cast<u64*>(base + (long)(r0 + 1) * stride)     = q2;
  *reinterpret_cast<u64*>(base + (long)(r0 + 1) * stride + 8) = q3;
}
// Fused dual-quarter poll for layer 1 (payl0[t] and payl1[t-1], one spin).
static __device__ __forceinline__ void poll_fetch_q2(const u64* p0T, const u64* p1T,
                                                     int wv, int lane, char* buf) {
  const u64* p0 = p0T + wv * 256 + lane * 4;
  const u64* p1 = p1T + wv * 256 + lane * 4;
  u64 a0, a1, a2, a3, b0, b1, b2, b3;
  int guard = 0;
  for (;;) {
    a0 = cload(p0);     a1 = cload(p0 + 1);
    a2 = cload(p0 + 2); a3 = cload(p0 + 3);
    b0 = cload(p1);     b1 = cload(p1 + 1);
    b2 = cload(p1 + 2); b3 = cload(p1 + 3);
    int ok = (a0 != SENT64) & (a1 != SENT64) & (a2 != SENT64) & (a3 != SENT64) &
             (b0 != SENT64) & (b1 != SENT64) & (b2 != SENT64) & (b3 != SENT64);
    if (__all(ok)) break;
    if (++guard > GUARD_MAX) break;
  }
  char* base0 = buf + wv * 256 + (lane >> 2) * 16;
  const int r0 = (lane & 3) * 2;
  *reinterpret_cast<u64*>(base0 + (long)r0 * STR1)           = a0;
  *reinterpret_cast<u64*>(base0 + (long)r0 * STR1 + 8)       = a1;
  *reinterpret_cast<u64*>(base0 + (long)(r0 + 1) * STR1)     = a2;
  *reinterpret_cast<u64*>(base0 + (long)(r0 + 1) * STR1 + 8) = a3;
  char* base1 = base0 + 1024;
  *reinterpret_cast<u64*>(base1 + (long)r0 * STR1)           = b0;
  *reinterpret_cast<u64*>(base1 + (long)r0 * STR1 + 8)       = b1;
  *reinterpret_cast<u64*>(base1 + (long)(r0 + 1) * STR1)     = b2;
  *reinterpret_cast<u64*>(base1 + (long)(r0 + 1) * STR1 + 8) = b3;
}

// fp32 -> bf16 elementwise (n multiple of 4)
__global__ __launch_bounds__(256)
void cvt_f32_bf16(const float* __restrict__ src, bf16* __restrict__ dst, int n) {
  int i = (blockIdx.x * 256 + threadIdx.x) * 4;
  if (i < n) {
    floatx4 v = *reinterpret_cast<const floatx4*>(src + i);
    short4v o;
    #pragma unroll
    for (int r = 0; r < 4; ++r) o[r] = f2bs(v[r]);
    *reinterpret_cast<short4v*>(dst + i) = o;
  }
}

// ---------------------------------------------------------------------------
// Layer-0 input projection (unchanged).
// ---------------------------------------------------------------------------
__global__ __launch_bounds__(256)
void gemm_proj(const float* __restrict__ Af, const bf16* __restrict__ W,
               const float* __restrict__ bias, bf16* __restrict__ out,
               int K, int strideB, int strideT)
{
  const int lane  = threadIdx.x & 63;
  const int wave  = threadIdx.x >> 6;
  const int q     = lane >> 4;
  const int c     = lane & 15;
  const int mtile = blockIdx.x;
  const int nbase = blockIdx.y * 256 + wave * 64;
  const int m     = mtile * 16 + c;

  const long abase = (long)(m & 7) * strideB + (long)(m >> 3) * strideT + q * 8;
  const bf16* W0 = W + (long)(nbase +  0 + c) * K + q * 8;
  const bf16* W1 = W + (long)(nbase + 16 + c) * K + q * 8;
  const bf16* W2 = W + (long)(nbase + 32 + c) * K + q * 8;
  const bf16* W3 = W + (long)(nbase + 48 + c) * K + q * 8;

  floatx4 acc0 = {0.f, 0.f, 0.f, 0.f};
  floatx4 acc1 = acc0, acc2 = acc0, acc3 = acc0;
  const int nk = K >> 5;
  for (int kt = 0; kt < nk; ++kt) {
    short8 a;
    floatx4 lo = *reinterpret_cast<const floatx4*>(Af + abase + kt * 32);
    floatx4 hi = *reinterpret_cast<const floatx4*>(Af + abase + kt * 32 + 4);
    #pragma unroll
    for (int r = 0; r < 4; ++r) { a[r] = f2bs(lo[r]); a[4 + r] = f2bs(hi[r]); }
    short8 b0 = *reinterpret_cast<const short8*>(W0 + kt * 32);
    short8 b1 = *reinterpret_cast<const short8*>(W1 + kt * 32);
    short8 b2 = *reinterpret_cast<const short8*>(W2 + kt * 32);
    short8 b3 = *reinterpret_cast<const short8*>(W3 + kt * 32);
    acc0 = mfma_bf16(a, b0, acc0);
    acc1 = mfma_bf16(a, b1, acc1);
    acc2 = mfma_bf16(a, b2, acc2);
    acc3 = mfma_bf16(a, b3, acc3);
  }

  floatx4 accs[4] = {acc0, acc1, acc2, acc3};
  #pragma unroll
  for (int nt = 0; nt < 4; ++nt) {
    const int n = nbase + nt * 16 + c;
    const float bv = bias[n];
    #pragma unroll
    for (int r = 0; r < 4; ++r) {
      const int mrow = mtile * 16 + q * 4 + r;
      out[(long)mrow * 2048 + n] = __float2bfloat16(accs[nt][r] + bv);
    }
  }
}

// ---------------------------------------------------------------------------
// Fused 2-layer persistent recurrence, XCD0-clustered. 512 blocks x 256 thr.
// ---------------------------------------------------------------------------
__global__ __launch_bounds__(256)
void lstm_fused(const bf16* __restrict__ wx, const bf16* __restrict__ Ub0,
                const bf16* __restrict__ Wb1, const bf16* __restrict__ Ub1,
                const float* __restrict__ ub0, const float* __restrict__ w1b,
                const float* __restrict__ u1b, float* __restrict__ out,
                u64* __restrict__ payl0, u64* __restrict__ payl1,
                unsigned int* __restrict__ done, unsigned int* __restrict__ claim)
{
  __shared__ char lds[2 * BUFSZ];   // double-buffered shared h staging
  __shared__ int s_ticket;
  if (threadIdx.x == 0) {
    int xcd = 0;
    asm volatile("s_getreg_b32 %0, hwreg(HW_REG_XCC_ID)" : "=s"(xcd));
    int tk = -1;
    if ((xcd & 7) == 0) {
      unsigned int t = __hip_atomic_fetch_add(claim, 1u, __ATOMIC_RELAXED,
                                              __HIP_MEMORY_SCOPE_AGENT);
      if (t < (unsigned)N_TICK) tk = (int)t;
    }
    s_ticket = tk;
  }
  __syncthreads();
  const int ticket = s_ticket;

  if (ticket < 0) {
    // ---------------- heater (all non-claimed blocks) ----------------
    float a0 = (float)threadIdx.x, a1 = a0 + 1.f, a2 = a0 + 2.f, a3 = a0 + 3.f;
    float a4 = a0 + 4.f, a5 = a0 + 5.f, a6 = a0 + 6.f, a7 = a0 + 7.f;
    const float xm = 1.0000001f, ya = 1e-7f;
    int g = 0;
    for (;;) {
      #pragma unroll
      for (int it = 0; it < 64; ++it) {
        asm volatile("v_fmac_f32 %0, %1, %2" : "+v"(a0) : "v"(xm), "v"(ya));
        asm volatile("v_fmac_f32 %0, %1, %2" : "+v"(a1) : "v"(xm), "v"(ya));
        asm volatile("v_fmac_f32 %0, %1, %2" : "+v"(a2) : "v"(xm), "v"(ya));
        asm volatile("v_fmac_f32 %0, %1, %2" : "+v"(a3) : "v"(xm), "v"(ya));
        asm volatile("v_fmac_f32 %0, %1, %2" : "+v"(a4) : "v"(xm), "v"(ya));
        asm volatile("v_fmac_f32 %0, %1, %2" : "+v"(a5) : "v"(xm), "v"(ya));
        asm volatile("v_fmac_f32 %0, %1, %2" : "+v"(a6) : "v"(xm), "v"(ya));
        asm volatile("v_fmac_f32 %0, %1, %2" : "+v"(a7) : "v"(xm), "v"(ya));
      }
      ++g;
      if ((g & 31) == 0) {           // poll rarely: keeps the MALL line quiet
        if (__hip_atomic_load(done, __ATOMIC_RELAXED,
                              __HIP_MEMORY_SCOPE_AGENT) >= (unsigned)N_TICK) break;
      }
      if (g > (1 << 16)) break;
    }
    return;
  }

  // ---------------- recurrence (4 waves of the 32 claimed blocks) ----------
  asm volatile("s_setprio 3" ::: "memory");
  const int wv    = threadIdx.x >> 6;
  const int lane  = threadIdx.x & 63;
  const int q     = lane >> 4;
  const int b     = lane & 15;
  const int layer = ticket >> 4;          // 0..1
  const int grp   = ticket & 15;          // 0..15
  const int blk   = grp * 4 + wv;         // 0..63
  const int jbase = blk * 8;
  const int jj    = jbase + (q & 1) * 4;

  const int row0 = (b < 8) ? (jbase + b) : (512 + jbase + b - 8);           // i | f
  const int row1 = (b < 8) ? (1024 + jbase + b) : (1536 + jbase + b - 8);   // g | o

  float* hh = out + ((layer == 0) ? HH_OFF : HH_OFF + 4096);
  float* cc = out + ((layer == 0) ? CC_OFF : CC_OFF + 4096);

  if (layer == 0) {
    // ---- Layer 0: K=512 (U0 * h1(t-1)) + precomputed wx ----
    short8 a0[16], a1[16];
    {
      const bf16* U0p = Ub0 + (long)row0 * 512 + q * 8;
      const bf16* U1p = Ub0 + (long)row1 * 512 + q * 8;
      #pragma unroll
      for (int kt = 0; kt < 16; ++kt) {
        a0[kt] = *reinterpret_cast<const short8*>(U0p + kt * 32);
        a1[kt] = *reinterpret_cast<const short8*>(U1p + kt * 32);
      }
    }
    float ubi[4], ubf[4], ubg[4], ubo[4];
    #pragma unroll
    for (int r = 0; r < 4; ++r) {
      ubi[r] = ub0[        jj + r];
      ubf[r] = ub0[ 512 + jj + r];
      ubg[r] = ub0[1024 + jj + r];
      ubo[r] = ub0[1536 + jj + r];
    }
    float cst[4] = {0.f, 0.f, 0.f, 0.f};

    // wx prefetch pipeline: regs hold step t while loop body issues t+1.
    const bf16* wxbase = wx + (b & 7) * 2048 + jj;
    short4v vi = *reinterpret_cast<const short4v*>(wxbase);
    short4v vf = *reinterpret_cast<const short4v*>(wxbase + 512);
    short4v vg = *reinterpret_cast<const short4v*>(wxbase + 1024);
    short4v vo = *reinterpret_cast<const short4v*>(wxbase + 1536);

    for (int t = 0; t < T_STEPS; ++t) {
      float wxi[4], wxf[4], wxg[4], wxo[4];
      #pragma unroll
      for (int r = 0; r < 4; ++r) {
        wxi[r] = bs2f(vi[r]); wxf[r] = bs2f(vf[r]);
        wxg[r] = bs2f(vg[r]); wxo[r] = bs2f(vo[r]);
      }
      if (t + 1 < T_STEPS) {
        const bf16* wn = wxbase + (long)(t + 1) * 16384;
        vi = *reinterpret_cast<const short4v*>(wn);
        vf = *reinterpret_cast<const short4v*>(wn + 512);
        vg = *reinterpret_cast<const short4v*>(wn + 1024);
        vo = *reinterpret_cast<const short4v*>(wn + 1536);
      }

      char* buf = lds + (t & 1) * BUFSZ;
      floatx4 acc0 = {0.f, 0.f, 0.f, 0.f};
      floatx4 acc1 = {0.f, 0.f, 0.f, 0.f};

      if (t > 0)
        poll_fetch_q(payl0 + (long)(t - 1) * 1024, wv, lane, buf, STR0, 0);
      __syncthreads();
      if (t > 0) {
        #pragma unroll
        for (int kt = 0; kt < 16; ++kt) {
          short8 hb = *reinterpret_cast<const short8*>(
              buf + (b & 7) * STR0 + kt * 64 + q * 16);
          acc0 = mfma_bf16(a0[kt], hb, acc0);
          acc1 = mfma_bf16(a1[kt], hb, acc1);
        }
      }

      float fsh[4], osh[4];
      #pragma unroll
      for (int r = 0; r < 4; ++r) {
        fsh[r] = __shfl_xor(acc0[r], 32, 64);
        osh[r] = __shfl_xor(acc1[r], 32, 64);
      }

      if (q < 2 && b < 8) {
        short4v hp4; floatx4 hf4, cf4;
        #pragma unroll
        for (int r = 0; r < 4; ++r) {
          const float pi = acc0[r] + wxi[r] + ubi[r];
          const float pf = fsh[r]  + wxf[r] + ubf[r];
          const float pg = acc1[r] + wxg[r] + ubg[r];
          const float po = osh[r]  + wxo[r] + ubo[r];
          const float it = sigm(pi), ft = sigm(pf);
          const float gt = tanhf_(pg), ot = sigm(po);
          const float cv = ft * cst[r] + it * gt;
          cst[r] = cv;
          const float hv = ot * fmaxf(cv, 0.f);
          hf4[r] = hv; cf4[r] = cv; hp4[r] = f2bs(hv);
        }
        union { short4v v; u64 u; } pk; pk.v = hp4;
        cstore(payl0 + (long)t * 1024 + blk * 16 + (b * 2 + (q & 1)), pk.u);
        if (t == T_STEPS - 1) {
          *reinterpret_cast<floatx4*>(hh + b * 512 + jj) = hf4;
          *reinterpret_cast<floatx4*>(cc + b * 512 + jj) = cf4;
        }
      }
    }
  } else {
    // ---- Layer 1: K=1024 ([W1|U1] * [h1(t); h2(t-1)]) ----
    short8 a0[32], a1[32];
    {
      const bf16* W0p = Wb1 + (long)row0 * 512 + q * 8;
      const bf16* W1p = Wb1 + (long)row1 * 512 + q * 8;
      const bf16* U0p = Ub1 + (long)row0 * 512 + q * 8;
      const bf16* U1p = Ub1 + (long)row1 * 512 + q * 8;
      #pragma unroll
      for (int kt = 0; kt < 16; ++kt) {
        a0[kt]      = *reinterpret_cast<const short8*>(W0p + kt * 32);
        a1[kt]      = *reinterpret_cast<const short8*>(W1p + kt * 32);
        a0[16 + kt] = *reinterpret_cast<const short8*>(U0p + kt * 32);
        a1[16 + kt] = *reinterpret_cast<const short8*>(U1p + kt * 32);
      }
    }
    float ubi[4], ubf[4], ubg[4], ubo[4];
    #pragma unroll
    for (int r = 0; r < 4; ++r) {
      ubi[r] = w1b[        jj + r] + u1b[        jj + r];
      ubf[r] = w1b[ 512 + jj + r] + u1b[ 512 + jj + r];
      ubg[r] = w1b[1024 + jj + r] + u1b[1024 + jj + r];
      ubo[r] = w1b[1536 + jj + r] + u1b[1536 + jj + r];
    }
    float cst[4] = {0.f, 0.f, 0.f, 0.f};

    for (int t = 0; t < T_STEPS; ++t) {
      char* buf = lds + (t & 1) * BUFSZ;
      floatx4 acc0 = {0.f, 0.f, 0.f, 0.f};
      floatx4 acc1 = {0.f, 0.f, 0.f, 0.f};

      if (t > 0) {
        poll_fetch_q2(payl0 + (long)t * 1024, payl1 + (long)(t - 1) * 1024,
                      wv, lane, buf);
      } else {
        poll_fetch_q(payl0, wv, lane, buf, STR1, 0);
      }
      __syncthreads();

      #pragma unroll
      for (int kt = 0; kt < 16; ++kt) {
        short8 hb = *reinterpret_cast<const short8*>(
            buf + (b & 7) * STR1 + kt * 64 + q * 16);
        acc0 = mfma_bf16(a0[kt], hb, acc0);
        acc1 = mfma_bf16(a1[kt], hb, acc1);
      }
      if (t > 0) {
        #pragma unroll
        for (int kt = 16; kt < 32; ++kt) {
          short8 hb = *reinterpret_cast<const short8*>(
              buf + (b & 7) * STR1 + kt * 64 + q * 16);
          acc0 = mfma_bf16(a0[kt], hb, acc0);
          acc1 = mfma_bf16(a1[kt], hb, acc1);
        }
      }

      float fsh[4], osh[4];
      #pragma unroll
      for (int r = 0; r < 4; ++r) {
        fsh[r] = __shfl_xor(acc0[r], 32, 64);
        osh[r] = __shfl_xor(acc1[r], 32, 64);
      }

      if (q < 2 && b < 8) {
        short4v hp4; floatx4 hf4, cf4;
        #pragma unroll
        for (int r = 0; r < 4; ++r) {
          const float pi = acc0[r] + ubi[r];
          const float pf = fsh[r]  + ubf[r];
          const float pg = acc1[r] + ubg[r];
          const float po = osh[r]  + ubo[r];
          const float it = sigm(pi), ft = sigm(pf);
          const float gt = tanhf_(pg), ot = sigm(po);
          const float cv = ft * cst[r] + it * gt;
          cst[r] = cv;
          const float hv = ot * fmaxf(cv, 0.f);
          hf4[r] = hv; cf4[r] = cv; hp4[r] = f2bs(hv);
        }
        union { short4v v; u64 u; } pk; pk.v = hp4;
        cstore(payl1 + (long)t * 1024 + blk * 16 + (b * 2 + (q & 1)), pk.u);
        *reinterpret_cast<floatx4*>(out + (long)b * 1048576 + (long)t * 512 + jj) = hf4;
        if (t == T_STEPS - 1) {
          *reinterpret_cast<floatx4*>(hh + b * 512 + jj) = hf4;
          *reinterpret_cast<floatx4*>(cc + b * 512 + jj) = cf4;
        }
      }
    }
  }

  // Signal heaters to exit (one per rec block).
  __syncthreads();
  if (threadIdx.x == 0) {
    __hip_atomic_fetch_add(done, 1u, __ATOMIC_RELAXED, __HIP_MEMORY_SCOPE_AGENT);
  }
}

extern "C" void kernel_launch(void* const* d_in, const int* in_sizes, int n_in,
                              void* d_out, int out_size, void* d_ws, size_t ws_size,
                              hipStream_t stream) {
  (void)in_sizes; (void)n_in; (void)out_size; (void)ws_size;
  const float* x   = (const float*)d_in[0];
  const float* w0w = (const float*)d_in[1];
  const float* w0b = (const float*)d_in[2];
  const float* u0w = (const float*)d_in[3];
  const float* u0b = (const float*)d_in[4];
  const float* w1w = (const float*)d_in[5];
  const float* w1b = (const float*)d_in[6];
  const float* u1w = (const float*)d_in[7];
  const float* u1b = (const float*)d_in[8];
  float* out = (float*)d_out;

  char* ws = (char*)d_ws;
  u64*  payl0 = (u64*)ws;
  u64*  payl1 = (u64*)(ws + (size_t)16777216);
  bf16* Wb0 = (bf16*)(ws + (size_t)33554432);
  bf16* Ub0 = (bf16*)(ws + (size_t)34603008);
  bf16* Wb1 = (bf16*)(ws + (size_t)36700160);
  bf16* Ub1 = (bf16*)(ws + (size_t)38797312);
  bf16* wx  = (bf16*)(ws + (size_t)40894464);
  unsigned int* done = (unsigned int*)(ws + (size_t)115343360);

  // Sentinel-fill payload arrays; zero the done+claim counters.
  hipMemsetAsync(ws, 0xFF, (size_t)33554432, stream);
  hipMemsetAsync(done, 0, 64, stream);

  // Weight conversions fp32 -> bf16.
  cvt_f32_bf16<<<512,  256, 0, stream>>>(w0w, Wb0, 524288);
  cvt_f32_bf16<<<1024, 256, 0, stream>>>(u0w, Ub0, 1048576);
  cvt_f32_bf16<<<1024, 256, 0, stream>>>(w1w, Wb1, 1048576);
  cvt_f32_bf16<<<1024, 256, 0, stream>>>(u1w, Ub1, 1048576);

  // Layer-0 input projection.
  dim3 gg(1024, 8, 1);
  gemm_proj<<<gg, 256, 0, stream>>>(x, Wb0, w0b, wx, 256, 2048 * 256, 256);

  // Fused 2-layer recurrence (XCD0-clustered) + heaters.
  lstm_fused<<<N_BLK, 256, 0, stream>>>(wx, Ub0, Wb1, Ub1, u0b, w1b, u1b,
                                        out, payl0, payl1, done, done + 1);
}